// Round 2
// baseline (746.670 us; speedup 1.0000x reference)
//
#include <hip/hip_runtime.h>

typedef __attribute__((ext_vector_type(4))) unsigned short us4;
typedef __attribute__((ext_vector_type(8))) unsigned short us8;
typedef __attribute__((ext_vector_type(8))) short s8;     // MFMA A/B fragment (8 bf16)
typedef __attribute__((ext_vector_type(4))) float f32x4;  // MFMA acc / float4

#define NTOK 32768
#define DIM_ 1024
#define HEADS_ 8
#define DH_ 64
#define WS_ 256
#define NWIN_ 128
#define INNER_ 512

__device__ __forceinline__ float b2f(unsigned short u) {
  union { unsigned u; float f; } x; x.u = ((unsigned)u) << 16; return x.f;
}
__device__ __forceinline__ unsigned short f2b(float f) {
  union { float f; unsigned u; } x; x.f = f;
  unsigned r = x.u + 0x7FFFu + ((x.u >> 16) & 1u);  // RNE
  return (unsigned short)(r >> 16);
}

// ---------------------------------------------------------------------------
// LayerNorm (f32 in) + half-row shift -> bf16 xs.
// xs[i][c<512] = xn[i-1][c] (row0 -> 0), xs[i][c>=512] = xn[i][c]
// ---------------------------------------------------------------------------
__global__ __launch_bounds__(256) void ln_shift(const float* __restrict__ x,
                                                const float* __restrict__ gamma,
                                                const float* __restrict__ beta,
                                                unsigned short* __restrict__ xs) {
  int row = blockIdx.x;
  int t = threadIdx.x;
  f32x4 v = ((const f32x4*)(x + (size_t)row * DIM_))[t];
  float sum = 0.f, ss = 0.f;
#pragma unroll
  for (int j = 0; j < 4; j++) { sum += v[j]; ss += v[j] * v[j]; }
#pragma unroll
  for (int off = 32; off >= 1; off >>= 1) {
    sum += __shfl_xor(sum, off);
    ss  += __shfl_xor(ss, off);
  }
  __shared__ float red[2][4];
  int wave = t >> 6, l = t & 63;
  if (l == 0) { red[0][wave] = sum; red[1][wave] = ss; }
  __syncthreads();
  sum = red[0][0] + red[0][1] + red[0][2] + red[0][3];
  ss  = red[1][0] + red[1][1] + red[1][2] + red[1][3];
  float mu = sum * (1.0f / DIM_);
  float var = ss * (1.0f / DIM_) - mu * mu;
  float rs = rsqrtf(var + 1e-5f);
  f32x4 g = ((const f32x4*)gamma)[t];
  f32x4 bb = ((const f32x4*)beta)[t];
  us4 o;
#pragma unroll
  for (int j = 0; j < 4; j++) o[j] = f2b((v[j] - mu) * rs * g[j] + bb[j]);
  int c0 = t * 4;
  if (c0 >= 512) {
    *(us4*)(xs + (size_t)row * DIM_ + c0) = o;
  } else {
    if (row + 1 < NTOK) *(us4*)(xs + (size_t)(row + 1) * DIM_ + c0) = o;
    if (row == 0) { us4 z = {0, 0, 0, 0}; *(us4*)(xs + c0) = z; }
  }
}

// ---------------------------------------------------------------------------
// f32 (R,C) -> bf16 (C,R) transpose; R,C multiples of 32. block (32,8)
// ---------------------------------------------------------------------------
__global__ __launch_bounds__(256) void transpose_f32_bf16(const float* __restrict__ in,
                                                          unsigned short* __restrict__ out,
                                                          int R, int C) {
  __shared__ unsigned short tile[32][33];
  int bx = blockIdx.x * 32, by = blockIdx.y * 32;
  int tx = threadIdx.x, ty = threadIdx.y;
#pragma unroll
  for (int i = 0; i < 32; i += 8) tile[ty + i][tx] = f2b(in[(size_t)(by + ty + i) * C + bx + tx]);
  __syncthreads();
#pragma unroll
  for (int i = 0; i < 32; i += 8) out[(size_t)(bx + ty + i) * R + by + tx] = tile[tx][ty + i];
}

// ---------------------------------------------------------------------------
// NT GEMM: C[M,N] = A[M,K] @ Bt[N,K]^T (+bias), bf16 in, f32 acc.
// 128x128 tile, BK=32, 256 thr (4 waves 2x2), reg-staged LDS w/ XOR swizzle.
// F32OUT ? f32 C : bf16 C.
// ---------------------------------------------------------------------------
template <bool F32OUT>
__global__ __launch_bounds__(256) void gemm_nt(const unsigned short* __restrict__ A,
                                               const unsigned short* __restrict__ Bt,
                                               void* __restrict__ Cv,
                                               const float* __restrict__ bias,
                                               int M, int N, int K) {
  __shared__ unsigned short sA[128 * 32];
  __shared__ unsigned short sB[128 * 32];
  int t = threadIdx.x;
  int l = t & 63, lg = l >> 4, ll = l & 15;
  int wave = t >> 6;
  int wm = wave >> 1, wn = wave & 1;
  int m0 = blockIdx.y * 128, n0 = blockIdx.x * 128;

  const f32x4 fz = {0.f, 0.f, 0.f, 0.f};
  f32x4 acc[4][4];
#pragma unroll
  for (int m = 0; m < 4; m++)
#pragma unroll
    for (int n = 0; n < 4; n++) acc[m][n] = fz;

  int srow = t >> 2;                      // staging row 0..63
  int wbyte = (srow * 64 + (t & 3) * 16) ^ ((srow & 7) << 4);
  const unsigned short* ga = A + (size_t)(m0 + srow) * K + (t & 3) * 8;
  const unsigned short* gb = Bt + (size_t)(n0 + srow) * K + (t & 3) * 8;
  int nk = K >> 5;
  for (int kt = 0; kt < nk; kt++) {
    us8 a0 = *(const us8*)(ga);
    us8 a1 = *(const us8*)(ga + (size_t)64 * K);
    us8 b0 = *(const us8*)(gb);
    us8 b1 = *(const us8*)(gb + (size_t)64 * K);
    ga += 32; gb += 32;
    __syncthreads();
    *(us8*)((char*)sA + wbyte) = a0;
    *(us8*)((char*)sA + 4096 + wbyte) = a1;
    *(us8*)((char*)sB + wbyte) = b0;
    *(us8*)((char*)sB + 4096 + wbyte) = b1;
    __syncthreads();
    s8 af[4], bf[4];
#pragma unroll
    for (int m = 0; m < 4; m++) {
      int r = wm * 64 + m * 16 + ll;
      af[m] = *(const s8*)((const char*)sA + ((r * 64 + lg * 16) ^ ((r & 7) << 4)));
    }
#pragma unroll
    for (int n = 0; n < 4; n++) {
      int r = wn * 64 + n * 16 + ll;
      bf[n] = *(const s8*)((const char*)sB + ((r * 64 + lg * 16) ^ ((r & 7) << 4)));
    }
#pragma unroll
    for (int m = 0; m < 4; m++)
#pragma unroll
      for (int n = 0; n < 4; n++)
        acc[m][n] = __builtin_amdgcn_mfma_f32_16x16x32_bf16(af[m], bf[n], acc[m][n], 0, 0, 0);
  }
#pragma unroll
  for (int n = 0; n < 4; n++) {
    int col = n0 + wn * 64 + n * 16 + ll;
    float bs = bias ? bias[col] : 0.0f;
#pragma unroll
    for (int m = 0; m < 4; m++) {
#pragma unroll
      for (int r = 0; r < 4; r++) {
        int row = m0 + wm * 64 + m * 16 + lg * 4 + r;
        if (F32OUT) ((float*)Cv)[(size_t)row * N + col] = acc[m][n][r] + bs;
        else ((unsigned short*)Cv)[(size_t)row * N + col] = f2b(acc[m][n][r] + bs);
      }
    }
  }
}

// ---------------------------------------------------------------------------
// RoPE on q,k thirds of qkv (bf16) with f32 sin/cos -> head-major (8, N, 64)
// ---------------------------------------------------------------------------
__global__ __launch_bounds__(256) void rotary_qk(const unsigned short* __restrict__ qkv,
                                                 const float* __restrict__ sn,
                                                 const float* __restrict__ cs,
                                                 unsigned short* __restrict__ qh,
                                                 unsigned short* __restrict__ kh) {
  int gid = blockIdx.x * 256 + threadIdx.x;
  int n = gid >> 7;
  int col = (gid & 127) * 8;
  int d = col & 63;
  us8 v = *(const us8*)(qkv + (size_t)n * 1536 + col);
  float se[8], ce[8];
  *(f32x4*)se = *(const f32x4*)(sn + (size_t)n * 64 + d);
  *(f32x4*)(se + 4) = *(const f32x4*)(sn + (size_t)n * 64 + d + 4);
  *(f32x4*)ce = *(const f32x4*)(cs + (size_t)n * 64 + d);
  *(f32x4*)(ce + 4) = *(const f32x4*)(cs + (size_t)n * 64 + d + 4);
  us8 o;
#pragma unroll
  for (int p = 0; p < 4; p++) {
    float v0 = b2f(v[2 * p]), v1 = b2f(v[2 * p + 1]);
    o[2 * p]     = f2b(v0 * ce[2 * p] - v1 * se[2 * p]);
    o[2 * p + 1] = f2b(v1 * ce[2 * p + 1] + v0 * se[2 * p + 1]);
  }
  int third = col >> 9;
  int cw = col & 511;
  int h = cw >> 6;
  unsigned short* dst = third ? kh : qh;
  *(us8*)(dst + ((size_t)h * NTOK + n) * 64 + (cw & 63)) = o;
}

// ---------------------------------------------------------------------------
// RoPE on v third + transpose -> v_t (8, 64, N). block = 64n x 64d tile.
// ---------------------------------------------------------------------------
__global__ __launch_bounds__(256) void rotary_vT(const unsigned short* __restrict__ qkv,
                                                 const float* __restrict__ sn,
                                                 const float* __restrict__ cs,
                                                 unsigned short* __restrict__ vt) {
  __shared__ unsigned short tile[64][72];
  int nt = blockIdx.x, h = blockIdx.y;
  int t = threadIdx.x;
  int i = t >> 2;
  int cc = (t & 3) * 16;
  int n = nt * 64 + i;
  const unsigned short* src = qkv + (size_t)n * 1536 + 1024 + h * 64 + cc;
  us8 v0 = *(const us8*)src;
  us8 v1 = *(const us8*)(src + 8);
  float se[16], ce[16];
#pragma unroll
  for (int q = 0; q < 4; q++) {
    *(f32x4*)(se + 4 * q) = *(const f32x4*)(sn + (size_t)n * 64 + cc + 4 * q);
    *(f32x4*)(ce + 4 * q) = *(const f32x4*)(cs + (size_t)n * 64 + cc + 4 * q);
  }
#pragma unroll
  for (int p = 0; p < 4; p++) {
    float a0 = b2f(v0[2 * p]), a1 = b2f(v0[2 * p + 1]);
    tile[i][cc + 2 * p]     = f2b(a0 * ce[2 * p] - a1 * se[2 * p]);
    tile[i][cc + 2 * p + 1] = f2b(a1 * ce[2 * p + 1] + a0 * se[2 * p + 1]);
    float b0 = b2f(v1[2 * p]), b1 = b2f(v1[2 * p + 1]);
    tile[i][cc + 8 + 2 * p]     = f2b(b0 * ce[8 + 2 * p] - b1 * se[8 + 2 * p]);
    tile[i][cc + 8 + 2 * p + 1] = f2b(b1 * ce[8 + 2 * p + 1] + b0 * se[8 + 2 * p + 1]);
  }
  __syncthreads();
  int dd = t >> 2;
  int nc = (t & 3) * 16;
  us8 r0, r1;
#pragma unroll
  for (int j = 0; j < 8; j++) { r0[j] = tile[nc + j][dd]; r1[j] = tile[nc + 8 + j][dd]; }
  unsigned short* dst = vt + ((size_t)h * 64 + dd) * NTOK + (size_t)nt * 64 + nc;
  *(us8*)dst = r0;
  *(us8*)(dst + 8) = r1;
}

// ---------------------------------------------------------------------------
// Windowed lookback attention. block = (quarter, window, head), 4 waves.
// Each wave: 16 q-rows x 512 keys (prev window + current window).
// ---------------------------------------------------------------------------
__global__ __launch_bounds__(256) void attn_kernel(const unsigned short* __restrict__ qh,
                                                   const unsigned short* __restrict__ kh,
                                                   const unsigned short* __restrict__ vt,
                                                   unsigned short* __restrict__ ao) {
  __shared__ unsigned short p_lds[4][8192];  // 16KB per wave (16 x 512 bf16)
  int quarter = blockIdx.x, w = blockIdx.y, h = blockIdx.z;
  int t = threadIdx.x;
  int wave = t >> 6, l = t & 63, lg = l >> 4, ll = l & 15;
  const unsigned short* qb = qh + (size_t)h * NTOK * 64;
  const unsigned short* kb = kh + (size_t)h * NTOK * 64;
  const unsigned short* vb = vt + (size_t)h * 64 * NTOK;

  int qn = w * 256 + quarter * 64 + wave * 16 + ll;  // this lane's A-row (global token)
  s8 qf0 = *(const s8*)(qb + (size_t)qn * 64 + lg * 8);
  s8 qf1 = *(const s8*)(qb + (size_t)qn * 64 + 32 + lg * 8);

  const f32x4 fz = {0.f, 0.f, 0.f, 0.f};
  const s8 sz = {0, 0, 0, 0, 0, 0, 0, 0};
  f32x4 s[32];
#pragma unroll
  for (int jt = 0; jt < 32; jt++) s[jt] = fz;

  int n0 = w * 256 - 256;
#pragma unroll
  for (int jt = 0; jt < 32; jt++) {
    int n = n0 + jt * 16 + ll;  // key token; <0 only for window 0 lookback
    s8 kf0 = sz, kf1 = sz;
    if (n >= 0) {
      kf0 = *(const s8*)(kb + (size_t)n * 64 + lg * 8);
      kf1 = *(const s8*)(kb + (size_t)n * 64 + 32 + lg * 8);
    }
    s[jt] = __builtin_amdgcn_mfma_f32_16x16x32_bf16(qf0, kf0, s[jt], 0, 0, 0);
    s[jt] = __builtin_amdgcn_mfma_f32_16x16x32_bf16(qf1, kf1, s[jt], 0, 0, 0);
  }

  // masked softmax; C rows at (lg*4 + r), cols at jt*16 + ll
  int iw = quarter * 64 + wave * 16 + lg * 4;  // within-window query row base
  float inv[4];
#pragma unroll
  for (int r = 0; r < 4; r++) {
    int qi = iw + r;
    float m = -3.0e38f;
#pragma unroll
    for (int jt = 0; jt < 32; jt++) {
      int j = jt * 16 + ll;
      bool ok = (j < 256) || ((j - 256) <= qi);
      float v = s[jt][r] * 0.125f;
      m = ok ? fmaxf(m, v) : m;
    }
#pragma unroll
    for (int off = 1; off < 16; off <<= 1) m = fmaxf(m, __shfl_xor(m, off));
    float dsum = 0.f;
#pragma unroll
    for (int jt = 0; jt < 32; jt++) {
      int j = jt * 16 + ll;
      bool ok = (j < 256) || ((j - 256) <= qi);
      float e = ok ? __expf(s[jt][r] * 0.125f - m) : 0.f;
      s[jt][r] = e;
      dsum += e;
    }
#pragma unroll
    for (int off = 1; off < 16; off <<= 1) dsum += __shfl_xor(dsum, off);
    inv[r] = 1.f / dsum;
  }

  // P (unnormalized) -> LDS, XOR-swizzled rows (kills b128 read conflicts)
  unsigned short* pl = p_lds[wave];
#pragma unroll
  for (int jt = 0; jt < 32; jt++) {
#pragma unroll
    for (int r = 0; r < 4; r++) {
      int rw = lg * 4 + r;
      int byte = (rw * 1024 + jt * 32 + ll * 2) ^ ((rw & 7) << 4);
      *(unsigned short*)((char*)pl + byte) = f2b(s[jt][r]);
    }
  }

  // PV: out(16x64) = P(16x512) @ V(512x64); V from transposed v_t
#pragma unroll
  for (int dt = 0; dt < 4; dt++) {
    f32x4 o = fz;
    int d = dt * 16 + ll;
#pragma unroll
    for (int ks = 0; ks < 16; ks++) {
      int byte = (ll * 1024 + ks * 64 + lg * 16) ^ ((ll & 7) << 4);
      s8 pa = *(const s8*)((const char*)pl + byte);
      int n = n0 + ks * 32 + lg * 8;
      s8 vf = sz;
      if (n >= 0) vf = *(const s8*)(vb + (size_t)d * NTOK + n);
      o = __builtin_amdgcn_mfma_f32_16x16x32_bf16(pa, vf, o, 0, 0, 0);
    }
#pragma unroll
    for (int r = 0; r < 4; r++) {
      int nrow = w * 256 + iw + r;
      ao[(size_t)nrow * INNER_ + h * 64 + dt * 16 + ll] = f2b(o[r] * inv[r]);
    }
  }
}

// ---------------------------------------------------------------------------
extern "C" void kernel_launch(void* const* d_in, const int* in_sizes, int n_in,
                              void* d_out, int out_size, void* d_ws, size_t ws_size,
                              hipStream_t stream) {
  const float* x     = (const float*)d_in[0];
  const float* sin_  = (const float*)d_in[1];
  const float* cos_  = (const float*)d_in[2];
  const float* gamma = (const float*)d_in[3];
  const float* beta  = (const float*)d_in[4];
  const float* w_qkv = (const float*)d_in[5];
  const float* w_out = (const float*)d_in[6];
  const float* b_out = (const float*)d_in[7];
  float* out = (float*)d_out;

  // ws layout (bytes). total needed = 205,520,896 (~196 MiB)
  char* ws = (char*)d_ws;
  const size_t OFF_WQT = 0;                    // 1536*1024*2 = 3,145,728
  const size_t OFF_WOT = 3145728;              // 1024*512*2  = 1,048,576
  const size_t OFF_XS  = 4194304;              // 32768*1024*2 = 67,108,864
  const size_t OFF_QKV = 71303168;             // 32768*1536*2 = 100,663,296
  const size_t OFF_VT  = 171966464;            // 8*64*32768*2 = 33,554,432
  const size_t NEEDED  = 205520896;
  if (ws_size < NEEDED) return;  // fail loudly (output stays poisoned)

  unsigned short* wqT = (unsigned short*)(ws + OFF_WQT);
  unsigned short* woT = (unsigned short*)(ws + OFF_WOT);
  unsigned short* xs  = (unsigned short*)(ws + OFF_XS);
  unsigned short* qkv = (unsigned short*)(ws + OFF_QKV);
  unsigned short* vt  = (unsigned short*)(ws + OFF_VT);
  unsigned short* qh  = xs;                                   // reuse xs after gemm1
  unsigned short* kh  = (unsigned short*)(ws + OFF_XS + 33554432);
  unsigned short* ao  = qkv;                                  // reuse qkv after rotary

  transpose_f32_bf16<<<dim3(1536 / 32, 1024 / 32), dim3(32, 8), 0, stream>>>(w_qkv, wqT, 1024, 1536);
  transpose_f32_bf16<<<dim3(1024 / 32, 512 / 32), dim3(32, 8), 0, stream>>>(w_out, woT, 512, 1024);
  ln_shift<<<NTOK, 256, 0, stream>>>(x, gamma, beta, xs);
  gemm_nt<false><<<dim3(1536 / 128, NTOK / 128), 256, 0, stream>>>(xs, wqT, qkv, nullptr, NTOK, 1536, 1024);
  rotary_qk<<<(NTOK * 128) / 256, 256, 0, stream>>>(qkv, sin_, cos_, qh, kh);
  rotary_vT<<<dim3(NTOK / 64, HEADS_), 256, 0, stream>>>(qkv, sin_, cos_, vt);
  attn_kernel<<<dim3(4, NWIN_, HEADS_), 256, 0, stream>>>(qh, kh, vt, ao);
  gemm_nt<true><<<dim3(1024 / 128, NTOK / 128), 256, 0, stream>>>(ao, woT, out, b_out, NTOK, 1024, 512);
}

// Round 3
// 505.912 us; speedup vs baseline: 1.4759x; 1.4759x over previous
//
#include <hip/hip_runtime.h>

typedef __attribute__((ext_vector_type(4))) unsigned short us4;
typedef __attribute__((ext_vector_type(8))) unsigned short us8;
typedef __attribute__((ext_vector_type(8))) short s8;     // MFMA A/B fragment (8 bf16)
typedef __attribute__((ext_vector_type(4))) float f32x4;  // MFMA acc / float4

#define NTOK 32768
#define DIM_ 1024
#define HEADS_ 8
#define DH_ 64
#define WS_ 256
#define NWIN_ 128
#define INNER_ 512

__device__ __forceinline__ float b2f(unsigned short u) {
  union { unsigned u; float f; } x; x.u = ((unsigned)u) << 16; return x.f;
}
__device__ __forceinline__ unsigned short f2b(float f) {
  union { float f; unsigned u; } x; x.f = f;
  unsigned r = x.u + 0x7FFFu + ((x.u >> 16) & 1u);  // RNE
  return (unsigned short)(r >> 16);
}

// global -> LDS direct DMA, 16B per lane. LDS dest = wave-uniform base + lane*16.
__device__ __forceinline__ void gload_lds16(const unsigned short* g, void* l) {
  __builtin_amdgcn_global_load_lds((const __attribute__((address_space(1))) void*)g,
                                   (__attribute__((address_space(3))) void*)l, 16, 0, 0);
}

// ---------------------------------------------------------------------------
// LayerNorm (f32 in) + half-row shift -> bf16 xs.
// ---------------------------------------------------------------------------
__global__ __launch_bounds__(256) void ln_shift(const float* __restrict__ x,
                                                const float* __restrict__ gamma,
                                                const float* __restrict__ beta,
                                                unsigned short* __restrict__ xs) {
  int row = blockIdx.x;
  int t = threadIdx.x;
  f32x4 v = ((const f32x4*)(x + (size_t)row * DIM_))[t];
  float sum = 0.f, ss = 0.f;
#pragma unroll
  for (int j = 0; j < 4; j++) { sum += v[j]; ss += v[j] * v[j]; }
#pragma unroll
  for (int off = 32; off >= 1; off >>= 1) {
    sum += __shfl_xor(sum, off);
    ss  += __shfl_xor(ss, off);
  }
  __shared__ float red[2][4];
  int wave = t >> 6, l = t & 63;
  if (l == 0) { red[0][wave] = sum; red[1][wave] = ss; }
  __syncthreads();
  sum = red[0][0] + red[0][1] + red[0][2] + red[0][3];
  ss  = red[1][0] + red[1][1] + red[1][2] + red[1][3];
  float mu = sum * (1.0f / DIM_);
  float var = ss * (1.0f / DIM_) - mu * mu;
  float rs = rsqrtf(var + 1e-5f);
  f32x4 g = ((const f32x4*)gamma)[t];
  f32x4 bb = ((const f32x4*)beta)[t];
  us4 o;
#pragma unroll
  for (int j = 0; j < 4; j++) o[j] = f2b((v[j] - mu) * rs * g[j] + bb[j]);
  int c0 = t * 4;
  if (c0 >= 512) {
    *(us4*)(xs + (size_t)row * DIM_ + c0) = o;
  } else {
    if (row + 1 < NTOK) *(us4*)(xs + (size_t)(row + 1) * DIM_ + c0) = o;
    if (row == 0) { us4 z = {0, 0, 0, 0}; *(us4*)(xs + c0) = z; }
  }
}

// ---------------------------------------------------------------------------
// f32 (R,C) -> bf16 (C,R) transpose; R,C multiples of 32. block (32,8)
// ---------------------------------------------------------------------------
__global__ __launch_bounds__(256) void transpose_f32_bf16(const float* __restrict__ in,
                                                          unsigned short* __restrict__ out,
                                                          int R, int C) {
  __shared__ unsigned short tile[32][33];
  int bx = blockIdx.x * 32, by = blockIdx.y * 32;
  int tx = threadIdx.x, ty = threadIdx.y;
#pragma unroll
  for (int i = 0; i < 32; i += 8) tile[ty + i][tx] = f2b(in[(size_t)(by + ty + i) * C + bx + tx]);
  __syncthreads();
#pragma unroll
  for (int i = 0; i < 32; i += 8) out[(size_t)(bx + ty + i) * R + by + tx] = tile[tx][ty + i];
}

// ---------------------------------------------------------------------------
// NT GEMM (m97 structure): C[M,N] = A[M,K] @ Bt[N,K]^T (+bias), bf16 in.
// 128x128 tile, BK=32, 4 waves, global_load_lds w16, source-swizzled LDS.
// LDS[r][u] = G[r][u ^ ((r>>1)&3)]  (u = 16B unit index 0..3 within 64B row)
// ---------------------------------------------------------------------------
template <bool F32OUT>
__global__ __launch_bounds__(256) void gemm_nt(const unsigned short* __restrict__ A,
                                               const unsigned short* __restrict__ Bt,
                                               void* __restrict__ Cv,
                                               const float* __restrict__ bias,
                                               int M, int N, int K) {
  __shared__ unsigned short sA[128 * 32];
  __shared__ unsigned short sB[128 * 32];
  int t = threadIdx.x;
  int l = t & 63, lg = l >> 4, ll = l & 15;
  int wave = t >> 6;
  int wm = wave >> 1, wn = wave & 1;
  int m0 = blockIdx.y * 128, n0 = blockIdx.x * 128;

  const f32x4 fz = {0.f, 0.f, 0.f, 0.f};
  f32x4 acc[4][4];
#pragma unroll
  for (int m = 0; m < 4; m++)
#pragma unroll
    for (int n = 0; n < 4; n++) acc[m][n] = fz;

  // staging: wave covers rows wave*32..+32 of A and Bt (2 issues of 16 rows each)
  int srow = wave * 32 + (l >> 2);                 // issue0 row; issue1 = +16
  int sunit = (l & 3) ^ ((l >> 3) & 3);            // pre-swizzled source 16B-unit
  const unsigned short* gA = A + (size_t)(m0 + srow) * K + sunit * 8;
  const unsigned short* gB = Bt + (size_t)(n0 + srow) * K + sunit * 8;
  char* lA0 = (char*)sA + wave * 2048;
  char* lB0 = (char*)sB + wave * 2048;

  int fsw = ((ll >> 1) & 3);                       // frag-read swizzle key
  int nk = K >> 5;
  for (int kt = 0; kt < nk; kt++) {
    __syncthreads();
    gload_lds16(gA, lA0);
    gload_lds16(gA + (size_t)16 * K, lA0 + 1024);
    gload_lds16(gB, lB0);
    gload_lds16(gB + (size_t)16 * K, lB0 + 1024);
    gA += 32; gB += 32;
    __syncthreads();
    s8 af[4], bf[4];
#pragma unroll
    for (int m = 0; m < 4; m++) {
      int r = wm * 64 + m * 16 + ll;
      af[m] = *(const s8*)((const char*)sA + r * 64 + ((lg ^ fsw) << 4));
    }
#pragma unroll
    for (int n = 0; n < 4; n++) {
      int r = wn * 64 + n * 16 + ll;
      bf[n] = *(const s8*)((const char*)sB + r * 64 + ((lg ^ fsw) << 4));
    }
#pragma unroll
    for (int m = 0; m < 4; m++)
#pragma unroll
      for (int n = 0; n < 4; n++)
        acc[m][n] = __builtin_amdgcn_mfma_f32_16x16x32_bf16(af[m], bf[n], acc[m][n], 0, 0, 0);
  }
#pragma unroll
  for (int n = 0; n < 4; n++) {
    int col = n0 + wn * 64 + n * 16 + ll;
    float bs = bias ? bias[col] : 0.0f;
#pragma unroll
    for (int m = 0; m < 4; m++) {
#pragma unroll
      for (int r = 0; r < 4; r++) {
        int row = m0 + wm * 64 + m * 16 + lg * 4 + r;
        if (F32OUT) ((float*)Cv)[(size_t)row * N + col] = acc[m][n][r] + bs;
        else ((unsigned short*)Cv)[(size_t)row * N + col] = f2b(acc[m][n][r] + bs);
      }
    }
  }
}

// ---------------------------------------------------------------------------
// RoPE on q,k thirds of qkv (bf16) with f32 sin/cos -> head-major (8, N, 64)
// ---------------------------------------------------------------------------
__global__ __launch_bounds__(256) void rotary_qk(const unsigned short* __restrict__ qkv,
                                                 const float* __restrict__ sn,
                                                 const float* __restrict__ cs,
                                                 unsigned short* __restrict__ qh,
                                                 unsigned short* __restrict__ kh) {
  int gid = blockIdx.x * 256 + threadIdx.x;
  int n = gid >> 7;
  int col = (gid & 127) * 8;
  int d = col & 63;
  us8 v = *(const us8*)(qkv + (size_t)n * 1536 + col);
  float se[8], ce[8];
  *(f32x4*)se = *(const f32x4*)(sn + (size_t)n * 64 + d);
  *(f32x4*)(se + 4) = *(const f32x4*)(sn + (size_t)n * 64 + d + 4);
  *(f32x4*)ce = *(const f32x4*)(cs + (size_t)n * 64 + d);
  *(f32x4*)(ce + 4) = *(const f32x4*)(cs + (size_t)n * 64 + d + 4);
  us8 o;
#pragma unroll
  for (int p = 0; p < 4; p++) {
    float v0 = b2f(v[2 * p]), v1 = b2f(v[2 * p + 1]);
    o[2 * p]     = f2b(v0 * ce[2 * p] - v1 * se[2 * p]);
    o[2 * p + 1] = f2b(v1 * ce[2 * p + 1] + v0 * se[2 * p + 1]);
  }
  int third = col >> 9;
  int cw = col & 511;
  int h = cw >> 6;
  unsigned short* dst = third ? kh : qh;
  *(us8*)(dst + ((size_t)h * NTOK + n) * 64 + (cw & 63)) = o;
}

// ---------------------------------------------------------------------------
// RoPE on v third + transpose -> v_t (8, 64, N). block = 64n x 64d tile.
// ---------------------------------------------------------------------------
__global__ __launch_bounds__(256) void rotary_vT(const unsigned short* __restrict__ qkv,
                                                 const float* __restrict__ sn,
                                                 const float* __restrict__ cs,
                                                 unsigned short* __restrict__ vt) {
  __shared__ unsigned short tile[64][72];
  int nt = blockIdx.x, h = blockIdx.y;
  int t = threadIdx.x;
  int i = t >> 2;
  int cc = (t & 3) * 16;
  int n = nt * 64 + i;
  const unsigned short* src = qkv + (size_t)n * 1536 + 1024 + h * 64 + cc;
  us8 v0 = *(const us8*)src;
  us8 v1 = *(const us8*)(src + 8);
  float se[16], ce[16];
#pragma unroll
  for (int q = 0; q < 4; q++) {
    *(f32x4*)(se + 4 * q) = *(const f32x4*)(sn + (size_t)n * 64 + cc + 4 * q);
    *(f32x4*)(ce + 4 * q) = *(const f32x4*)(cs + (size_t)n * 64 + cc + 4 * q);
  }
#pragma unroll
  for (int p = 0; p < 4; p++) {
    float a0 = b2f(v0[2 * p]), a1 = b2f(v0[2 * p + 1]);
    tile[i][cc + 2 * p]     = f2b(a0 * ce[2 * p] - a1 * se[2 * p]);
    tile[i][cc + 2 * p + 1] = f2b(a1 * ce[2 * p + 1] + a0 * se[2 * p + 1]);
    float b0 = b2f(v1[2 * p]), b1 = b2f(v1[2 * p + 1]);
    tile[i][cc + 8 + 2 * p]     = f2b(b0 * ce[8 + 2 * p] - b1 * se[8 + 2 * p]);
    tile[i][cc + 8 + 2 * p + 1] = f2b(b1 * ce[8 + 2 * p + 1] + b0 * se[8 + 2 * p + 1]);
  }
  __syncthreads();
  int dd = t >> 2;
  int nc = (t & 3) * 16;
  us8 r0, r1;
#pragma unroll
  for (int j = 0; j < 8; j++) { r0[j] = tile[nc + j][dd]; r1[j] = tile[nc + 8 + j][dd]; }
  unsigned short* dst = vt + ((size_t)h * 64 + dd) * NTOK + (size_t)nt * 64 + nc;
  *(us8*)dst = r0;
  *(us8*)(dst + 8) = r1;
}

// ---------------------------------------------------------------------------
// Windowed lookback attention, v2. block = (half, window, head), 8 waves.
// K chunks (128 keys) staged via global_load_lds w/ pre-swizzled source;
// V direct from L2-resident vt; P per-wave via swizzled LDS; S in registers.
// LDS: 16KB K + 8x4KB P = 48KB -> 3 blocks/CU.
// ---------------------------------------------------------------------------
__global__ __launch_bounds__(512) void attn_kernel(const unsigned short* __restrict__ qh,
                                                   const unsigned short* __restrict__ kh,
                                                   const unsigned short* __restrict__ vt,
                                                   unsigned short* __restrict__ ao) {
  __shared__ char k_lds[16384];        // 128 keys x 128B, unit-swizzled by (row&7)
  __shared__ char p_lds[8][4096];      // per-wave 16 rows x 256B, unit-swizzled
  int half = blockIdx.x, w = blockIdx.y, h = blockIdx.z;
  int t = threadIdx.x;
  int wave = t >> 6, l = t & 63, lg = l >> 4, ll = l & 15;
  const unsigned short* qb = qh + (size_t)h * NTOK * 64;
  const unsigned short* kb = kh + (size_t)h * NTOK * 64;
  const unsigned short* vb = vt + (size_t)h * 64 * NTOK;

  int qn = w * 256 + half * 128 + wave * 16 + ll;  // this lane's A-row (global token)
  s8 qf0 = *(const s8*)(qb + (size_t)qn * 64 + lg * 8);
  s8 qf1 = *(const s8*)(qb + (size_t)qn * 64 + 32 + lg * 8);

  const f32x4 fz = {0.f, 0.f, 0.f, 0.f};
  const s8 sz = {0, 0, 0, 0, 0, 0, 0, 0};
  f32x4 s[32];
#pragma unroll
  for (int jt = 0; jt < 32; jt++) s[jt] = fz;

  int n0 = w * 256 - 256;

  // K staging geometry: wave covers rows wave*16..+16 (2 issues of 8 rows)
  int krow = wave * 16 + (l >> 3);                 // issue0 row; issue1 = +8 (same swizzle)
  int kunit = (l & 7) ^ (krow & 7);
  char* kl0 = k_lds + wave * 2048;

  // ---- Phase 1: QK^T over 4 chunks of 128 keys ----
  for (int c = 0; c < 4; c++) {
    int cb = n0 + c * 128;
    __syncthreads();
    if (cb < 0) {  // window-0 lookback: zero-padded keys (participate in softmax)
      us8 z = {0, 0, 0, 0, 0, 0, 0, 0};
      *(us8*)(kl0 + l * 16) = z;
      *(us8*)(kl0 + 1024 + l * 16) = z;
    } else {
      const unsigned short* gk = kb + (size_t)(cb + krow) * 64 + kunit * 8;
      gload_lds16(gk, kl0);
      gload_lds16(gk + 512, kl0 + 1024);
    }
    __syncthreads();
#pragma unroll
    for (int nt = 0; nt < 8; nt++) {
      int r = nt * 16 + ll;
      s8 kf0 = *(const s8*)(k_lds + r * 128 + ((lg ^ (r & 7)) << 4));
      s8 kf1 = *(const s8*)(k_lds + r * 128 + (((4 + lg) ^ (r & 7)) << 4));
      s[c * 8 + nt] = __builtin_amdgcn_mfma_f32_16x16x32_bf16(qf0, kf0, s[c * 8 + nt], 0, 0, 0);
      s[c * 8 + nt] = __builtin_amdgcn_mfma_f32_16x16x32_bf16(qf1, kf1, s[c * 8 + nt], 0, 0, 0);
    }
  }

  // ---- masked softmax; C rows at (lg*4 + r), cols at jt*16 + ll ----
  int iw = half * 128 + wave * 16 + lg * 4;
  float inv[4];
#pragma unroll
  for (int r = 0; r < 4; r++) {
    int qi = iw + r;
    float m = -3.0e38f;
#pragma unroll
    for (int jt = 0; jt < 32; jt++) {
      int j = jt * 16 + ll;
      bool ok = (j < 256) || ((j - 256) <= qi);
      float v = s[jt][r] * 0.125f;
      m = ok ? fmaxf(m, v) : m;
    }
#pragma unroll
    for (int off = 1; off < 16; off <<= 1) m = fmaxf(m, __shfl_xor(m, off));
    float dsum = 0.f;
#pragma unroll
    for (int jt = 0; jt < 32; jt++) {
      int j = jt * 16 + ll;
      bool ok = (j < 256) || ((j - 256) <= qi);
      float e = ok ? __expf(s[jt][r] * 0.125f - m) : 0.f;
      s[jt][r] = e;
      dsum += e;
    }
#pragma unroll
    for (int off = 1; off < 16; off <<= 1) dsum += __shfl_xor(dsum, off);
    inv[r] = 1.f / dsum;
  }

  // pack P to bf16 pairs early (frees the 128 f32 of S before PV)
  unsigned p16[32][2];
#pragma unroll
  for (int jt = 0; jt < 32; jt++) {
    p16[jt][0] = (unsigned)f2b(s[jt][0]) | ((unsigned)f2b(s[jt][1]) << 16);
    p16[jt][1] = (unsigned)f2b(s[jt][2]) | ((unsigned)f2b(s[jt][3]) << 16);
  }

  // ---- Phase 2: PV over 4 chunks; P via own-wave LDS, V direct global ----
  char* pl = p_lds[wave];
  f32x4 o[4];
#pragma unroll
  for (int dt = 0; dt < 4; dt++) o[dt] = fz;

  for (int c = 0; c < 4; c++) {
    int cb = n0 + c * 128;
#pragma unroll
    for (int nt = 0; nt < 8; nt++) {
      int jt = c * 8 + nt;
      int cbyte = nt * 32 + ll * 2;
#pragma unroll
      for (int r = 0; r < 4; r++) {
        int rw = lg * 4 + r;
        unsigned val = (r & 1) ? (p16[jt][r >> 1] >> 16) : (p16[jt][r >> 1] & 0xFFFFu);
        *(unsigned short*)(pl + rw * 256 + (cbyte ^ ((rw & 7) << 4))) = (unsigned short)val;
      }
    }
    // own-wave write->read: compiler inserts lgkmcnt wait
#pragma unroll
    for (int dt = 0; dt < 4; dt++) {
#pragma unroll
      for (int ks = 0; ks < 4; ks++) {
        int gu = ks * 4 + lg;
        s8 pa = *(const s8*)(pl + ll * 256 + ((gu ^ (ll & 7)) << 4));
        int vrow = dt * 16 + ll;
        int n = cb + ks * 32 + lg * 8;
        s8 vf = sz;
        if (n >= 0) vf = *(const s8*)(vb + (size_t)vrow * NTOK + n);
        o[dt] = __builtin_amdgcn_mfma_f32_16x16x32_bf16(pa, vf, o[dt], 0, 0, 0);
      }
    }
  }

#pragma unroll
  for (int dt = 0; dt < 4; dt++) {
#pragma unroll
    for (int r = 0; r < 4; r++) {
      int nrow = w * 256 + iw + r;
      ao[(size_t)nrow * INNER_ + h * 64 + dt * 16 + ll] = f2b(o[dt][r] * inv[r]);
    }
  }
}

// ---------------------------------------------------------------------------
extern "C" void kernel_launch(void* const* d_in, const int* in_sizes, int n_in,
                              void* d_out, int out_size, void* d_ws, size_t ws_size,
                              hipStream_t stream) {
  const float* x     = (const float*)d_in[0];
  const float* sin_  = (const float*)d_in[1];
  const float* cos_  = (const float*)d_in[2];
  const float* gamma = (const float*)d_in[3];
  const float* beta  = (const float*)d_in[4];
  const float* w_qkv = (const float*)d_in[5];
  const float* w_out = (const float*)d_in[6];
  const float* b_out = (const float*)d_in[7];

  // ws layout (bytes). total needed = 205,520,896 (~196 MiB)
  char* ws = (char*)d_ws;
  const size_t OFF_WQT = 0;                    // 1536*1024*2 = 3,145,728
  const size_t OFF_WOT = 3145728;              // 1024*512*2  = 1,048,576
  const size_t OFF_XS  = 4194304;              // 32768*1024*2 = 67,108,864
  const size_t OFF_QKV = 71303168;             // 32768*1536*2 = 100,663,296
  const size_t OFF_VT  = 171966464;            // 8*64*32768*2 = 33,554,432
  const size_t NEEDED  = 205520896;
  if (ws_size < NEEDED) return;  // fail loudly (output stays poisoned)

  unsigned short* wqT = (unsigned short*)(ws + OFF_WQT);
  unsigned short* woT = (unsigned short*)(ws + OFF_WOT);
  unsigned short* xs  = (unsigned short*)(ws + OFF_XS);
  unsigned short* qkv = (unsigned short*)(ws + OFF_QKV);
  unsigned short* vt  = (unsigned short*)(ws + OFF_VT);
  unsigned short* qh  = xs;                                   // reuse xs after gemm1
  unsigned short* kh  = (unsigned short*)(ws + OFF_XS + 33554432);
  unsigned short* ao  = qkv;                                  // reuse qkv after rotary

  transpose_f32_bf16<<<dim3(1536 / 32, 1024 / 32), dim3(32, 8), 0, stream>>>(w_qkv, wqT, 1024, 1536);
  transpose_f32_bf16<<<dim3(1024 / 32, 512 / 32), dim3(32, 8), 0, stream>>>(w_out, woT, 512, 1024);
  ln_shift<<<NTOK, 256, 0, stream>>>(x, gamma, beta, xs);
  gemm_nt<false><<<dim3(1536 / 128, NTOK / 128), 256, 0, stream>>>(xs, wqT, qkv, nullptr, NTOK, 1536, 1024);
  rotary_qk<<<(NTOK * 128) / 256, 256, 0, stream>>>(qkv, sin_, cos_, qh, kh);
  rotary_vT<<<dim3(NTOK / 64, HEADS_), 256, 0, stream>>>(qkv, sin_, cos_, vt);
  attn_kernel<<<dim3(2, NWIN_, HEADS_), 512, 0, stream>>>(qh, kh, vt, ao);
  gemm_nt<true><<<dim3(1024 / 128, NTOK / 128), 256, 0, stream>>>(ao, woT, (void*)d_out, b_out, NTOK, 1024, 512);
}

// Round 4
// 392.894 us; speedup vs baseline: 1.9004x; 1.2877x over previous
//
#include <hip/hip_runtime.h>

typedef __attribute__((ext_vector_type(4))) unsigned short us4;
typedef __attribute__((ext_vector_type(8))) unsigned short us8;
typedef __attribute__((ext_vector_type(8))) short s8;      // MFMA A/B fragment (8 bf16)
typedef __attribute__((ext_vector_type(4))) float f32x4;   // 16x16 MFMA acc / float4
typedef __attribute__((ext_vector_type(16))) float f32x16; // 32x32 MFMA acc

#define NTOK 32768
#define DIM_ 1024
#define HEADS_ 8
#define DH_ 64
#define WS_ 256
#define NWIN_ 128
#define INNER_ 512

__device__ __forceinline__ float b2f(unsigned short u) {
  union { unsigned u; float f; } x; x.u = ((unsigned)u) << 16; return x.f;
}
__device__ __forceinline__ unsigned short f2b(float f) {
  union { float f; unsigned u; } x; x.f = f;
  unsigned r = x.u + 0x7FFFu + ((x.u >> 16) & 1u);  // RNE
  return (unsigned short)(r >> 16);
}
__device__ __forceinline__ unsigned pk2(float a, float b) {
  return (unsigned)f2b(a) | ((unsigned)f2b(b) << 16);
}
__device__ __forceinline__ s8 mk_s8(unsigned w0, unsigned w1, unsigned w2, unsigned w3) {
  union { unsigned u[4]; s8 v; } x;
  x.u[0] = w0; x.u[1] = w1; x.u[2] = w2; x.u[3] = w3;
  return x.v;
}

// global -> LDS direct DMA, 16B per lane. LDS dest = wave-uniform base + lane*16.
__device__ __forceinline__ void gload_lds16(const unsigned short* g, void* l) {
  __builtin_amdgcn_global_load_lds((const __attribute__((address_space(1))) void*)g,
                                   (__attribute__((address_space(3))) void*)l, 16, 0, 0);
}

// ---------------------------------------------------------------------------
// LayerNorm (f32 in) + half-row shift -> bf16 xs.
// ---------------------------------------------------------------------------
__global__ __launch_bounds__(256) void ln_shift(const float* __restrict__ x,
                                                const float* __restrict__ gamma,
                                                const float* __restrict__ beta,
                                                unsigned short* __restrict__ xs) {
  int row = blockIdx.x;
  int t = threadIdx.x;
  f32x4 v = ((const f32x4*)(x + (size_t)row * DIM_))[t];
  float sum = 0.f, ss = 0.f;
#pragma unroll
  for (int j = 0; j < 4; j++) { sum += v[j]; ss += v[j] * v[j]; }
#pragma unroll
  for (int off = 32; off >= 1; off >>= 1) {
    sum += __shfl_xor(sum, off);
    ss  += __shfl_xor(ss, off);
  }
  __shared__ float red[2][4];
  int wave = t >> 6, l = t & 63;
  if (l == 0) { red[0][wave] = sum; red[1][wave] = ss; }
  __syncthreads();
  sum = red[0][0] + red[0][1] + red[0][2] + red[0][3];
  ss  = red[1][0] + red[1][1] + red[1][2] + red[1][3];
  float mu = sum * (1.0f / DIM_);
  float var = ss * (1.0f / DIM_) - mu * mu;
  float rs = rsqrtf(var + 1e-5f);
  f32x4 g = ((const f32x4*)gamma)[t];
  f32x4 bb = ((const f32x4*)beta)[t];
  us4 o;
#pragma unroll
  for (int j = 0; j < 4; j++) o[j] = f2b((v[j] - mu) * rs * g[j] + bb[j]);
  int c0 = t * 4;
  if (c0 >= 512) {
    *(us4*)(xs + (size_t)row * DIM_ + c0) = o;
  } else {
    if (row + 1 < NTOK) *(us4*)(xs + (size_t)(row + 1) * DIM_ + c0) = o;
    if (row == 0) { us4 z = {0, 0, 0, 0}; *(us4*)(xs + c0) = z; }
  }
}

// ---------------------------------------------------------------------------
// f32 (R,C) -> bf16 (C,R) transpose; R,C multiples of 32. block (32,8)
// ---------------------------------------------------------------------------
__global__ __launch_bounds__(256) void transpose_f32_bf16(const float* __restrict__ in,
                                                          unsigned short* __restrict__ out,
                                                          int R, int C) {
  __shared__ unsigned short tile[32][33];
  int bx = blockIdx.x * 32, by = blockIdx.y * 32;
  int tx = threadIdx.x, ty = threadIdx.y;
#pragma unroll
  for (int i = 0; i < 32; i += 8) tile[ty + i][tx] = f2b(in[(size_t)(by + ty + i) * C + bx + tx]);
  __syncthreads();
#pragma unroll
  for (int i = 0; i < 32; i += 8) out[(size_t)(bx + ty + i) * R + by + tx] = tile[tx][ty + i];
}

// ---------------------------------------------------------------------------
// NT GEMM (m97 structure): C[M,N] = A[M,K] @ Bt[N,K]^T (+bias), bf16 in.
// 128x128 tile, BK=32, 4 waves, global_load_lds w16, source-swizzled LDS.
// ---------------------------------------------------------------------------
template <bool F32OUT>
__global__ __launch_bounds__(256) void gemm_nt(const unsigned short* __restrict__ A,
                                               const unsigned short* __restrict__ Bt,
                                               void* __restrict__ Cv,
                                               const float* __restrict__ bias,
                                               int M, int N, int K) {
  __shared__ unsigned short sA[128 * 32];
  __shared__ unsigned short sB[128 * 32];
  int t = threadIdx.x;
  int l = t & 63, lg = l >> 4, ll = l & 15;
  int wave = t >> 6;
  int wm = wave >> 1, wn = wave & 1;
  int m0 = blockIdx.y * 128, n0 = blockIdx.x * 128;

  const f32x4 fz = {0.f, 0.f, 0.f, 0.f};
  f32x4 acc[4][4];
#pragma unroll
  for (int m = 0; m < 4; m++)
#pragma unroll
    for (int n = 0; n < 4; n++) acc[m][n] = fz;

  int srow = wave * 32 + (l >> 2);                 // issue0 row; issue1 = +16
  int sunit = (l & 3) ^ ((l >> 3) & 3);            // pre-swizzled source 16B-unit
  const unsigned short* gA = A + (size_t)(m0 + srow) * K + sunit * 8;
  const unsigned short* gB = Bt + (size_t)(n0 + srow) * K + sunit * 8;
  char* lA0 = (char*)sA + wave * 2048;
  char* lB0 = (char*)sB + wave * 2048;

  int fsw = ((ll >> 1) & 3);                       // frag-read swizzle key
  int nk = K >> 5;
  for (int kt = 0; kt < nk; kt++) {
    __syncthreads();
    gload_lds16(gA, lA0);
    gload_lds16(gA + (size_t)16 * K, lA0 + 1024);
    gload_lds16(gB, lB0);
    gload_lds16(gB + (size_t)16 * K, lB0 + 1024);
    gA += 32; gB += 32;
    __syncthreads();
    s8 af[4], bf[4];
#pragma unroll
    for (int m = 0; m < 4; m++) {
      int r = wm * 64 + m * 16 + ll;
      af[m] = *(const s8*)((const char*)sA + r * 64 + ((lg ^ fsw) << 4));
    }
#pragma unroll
    for (int n = 0; n < 4; n++) {
      int r = wn * 64 + n * 16 + ll;
      bf[n] = *(const s8*)((const char*)sB + r * 64 + ((lg ^ fsw) << 4));
    }
#pragma unroll
    for (int m = 0; m < 4; m++)
#pragma unroll
      for (int n = 0; n < 4; n++)
        acc[m][n] = __builtin_amdgcn_mfma_f32_16x16x32_bf16(af[m], bf[n], acc[m][n], 0, 0, 0);
  }
#pragma unroll
  for (int n = 0; n < 4; n++) {
    int col = n0 + wn * 64 + n * 16 + ll;
    float bs = bias ? bias[col] : 0.0f;
#pragma unroll
    for (int m = 0; m < 4; m++) {
#pragma unroll
      for (int r = 0; r < 4; r++) {
        int row = m0 + wm * 64 + m * 16 + lg * 4 + r;
        if (F32OUT) ((float*)Cv)[(size_t)row * N + col] = acc[m][n][r] + bs;
        else ((unsigned short*)Cv)[(size_t)row * N + col] = f2b(acc[m][n][r] + bs);
      }
    }
  }
}

// ---------------------------------------------------------------------------
// RoPE on q,k thirds of qkv (bf16) with f32 sin/cos -> head-major (8, N, 64)
// ---------------------------------------------------------------------------
__global__ __launch_bounds__(256) void rotary_qk(const unsigned short* __restrict__ qkv,
                                                 const float* __restrict__ sn,
                                                 const float* __restrict__ cs,
                                                 unsigned short* __restrict__ qh,
                                                 unsigned short* __restrict__ kh) {
  int gid = blockIdx.x * 256 + threadIdx.x;
  int n = gid >> 7;
  int col = (gid & 127) * 8;
  int d = col & 63;
  us8 v = *(const us8*)(qkv + (size_t)n * 1536 + col);
  float se[8], ce[8];
  *(f32x4*)se = *(const f32x4*)(sn + (size_t)n * 64 + d);
  *(f32x4*)(se + 4) = *(const f32x4*)(sn + (size_t)n * 64 + d + 4);
  *(f32x4*)ce = *(const f32x4*)(cs + (size_t)n * 64 + d);
  *(f32x4*)(ce + 4) = *(const f32x4*)(cs + (size_t)n * 64 + d + 4);
  us8 o;
#pragma unroll
  for (int p = 0; p < 4; p++) {
    float v0 = b2f(v[2 * p]), v1 = b2f(v[2 * p + 1]);
    o[2 * p]     = f2b(v0 * ce[2 * p] - v1 * se[2 * p]);
    o[2 * p + 1] = f2b(v1 * ce[2 * p + 1] + v0 * se[2 * p + 1]);
  }
  int third = col >> 9;
  int cw = col & 511;
  int h = cw >> 6;
  unsigned short* dst = third ? kh : qh;
  *(us8*)(dst + ((size_t)h * NTOK + n) * 64 + (cw & 63)) = o;
}

// ---------------------------------------------------------------------------
// RoPE on v third + transpose -> v_t (8, 64, N). block = 64n x 64d tile.
// ---------------------------------------------------------------------------
__global__ __launch_bounds__(256) void rotary_vT(const unsigned short* __restrict__ qkv,
                                                 const float* __restrict__ sn,
                                                 const float* __restrict__ cs,
                                                 unsigned short* __restrict__ vt) {
  __shared__ unsigned short tile[64][72];
  int nt = blockIdx.x, h = blockIdx.y;
  int t = threadIdx.x;
  int i = t >> 2;
  int cc = (t & 3) * 16;
  int n = nt * 64 + i;
  const unsigned short* src = qkv + (size_t)n * 1536 + 1024 + h * 64 + cc;
  us8 v0 = *(const us8*)src;
  us8 v1 = *(const us8*)(src + 8);
  float se[16], ce[16];
#pragma unroll
  for (int q = 0; q < 4; q++) {
    *(f32x4*)(se + 4 * q) = *(const f32x4*)(sn + (size_t)n * 64 + cc + 4 * q);
    *(f32x4*)(ce + 4 * q) = *(const f32x4*)(cs + (size_t)n * 64 + cc + 4 * q);
  }
#pragma unroll
  for (int p = 0; p < 4; p++) {
    float a0 = b2f(v0[2 * p]), a1 = b2f(v0[2 * p + 1]);
    tile[i][cc + 2 * p]     = f2b(a0 * ce[2 * p] - a1 * se[2 * p]);
    tile[i][cc + 2 * p + 1] = f2b(a1 * ce[2 * p + 1] + a0 * se[2 * p + 1]);
    float b0 = b2f(v1[2 * p]), b1 = b2f(v1[2 * p + 1]);
    tile[i][cc + 8 + 2 * p]     = f2b(b0 * ce[8 + 2 * p] - b1 * se[8 + 2 * p]);
    tile[i][cc + 8 + 2 * p + 1] = f2b(b1 * ce[8 + 2 * p + 1] + b0 * se[8 + 2 * p + 1]);
  }
  __syncthreads();
  int dd = t >> 2;
  int nc = (t & 3) * 16;
  us8 r0, r1;
#pragma unroll
  for (int j = 0; j < 8; j++) { r0[j] = tile[nc + j][dd]; r1[j] = tile[nc + 8 + j][dd]; }
  unsigned short* dst = vt + ((size_t)h * 64 + dd) * NTOK + (size_t)nt * 64 + nc;
  *(us8*)dst = r0;
  *(us8*)(dst + 8) = r1;
}

// ---------------------------------------------------------------------------
// Windowed lookback attention, v3: 32x32 MFMA, swapped operands.
// block = (half, window, head), 4 waves x 32 q-rows. 8 chunks of 64 keys.
// QK^T = mfma(K, Q) -> S^T (lane owns q = lane&31); softmax in-register,
// no max-pass; P->bf16 + 2x permlane32_swap per 16-key tile = PV B-frag;
// PV = mfma(V^T, P^T) -> O^T. K dbuf + V single LDS via global_load_lds.
// ---------------------------------------------------------------------------
__global__ __launch_bounds__(256, 4) void attn_kernel(const unsigned short* __restrict__ qh,
                                                      const unsigned short* __restrict__ kh,
                                                      const unsigned short* __restrict__ vt,
                                                      unsigned short* __restrict__ ao) {
  __shared__ char kbuf[2][8192];   // 64 keys x 128B, unit-swizzled by (row&7)
  __shared__ char vbuf[8192];      // 64 d x 128B (64 keys), unit-swizzled by (d&7)
  int half = blockIdx.x, w = blockIdx.y, h = blockIdx.z;
  int t = threadIdx.x;
  int wave = t >> 6, l = t & 63;
  int l31 = l & 31, hi = l >> 5;
  const unsigned short* qb = qh + (size_t)h * NTOK * 64;
  const unsigned short* kb = kh + (size_t)h * NTOK * 64;
  const unsigned short* vb = vt + (size_t)h * 64 * NTOK;

  int qw = half * 128 + wave * 32 + l31;   // q within window
  int qn = w * 256 + qw;                   // global token
  s8 qf[4];
#pragma unroll
  for (int dht = 0; dht < 4; dht++)
    qf[dht] = *(const s8*)(qb + (size_t)qn * 64 + dht * 16 + hi * 8);

  f32x16 o0 = {}, o1 = {};
  float dsum = (w == 0) ? 128.f : 0.f;     // 256 zero-keys contribute exp(0)=1; split across hi halves
  int n0 = w * 256 - 256;
  int c0 = (w == 0) ? 4 : 0;

  // staging geometry (per wave: 16 rows = 2 issues of 8)
  int srow = wave * 16 + (l >> 3);
  int sunit = l & 7;

  // prologue: stage K(c0)
  {
    const unsigned short* g = kb + (size_t)(n0 + c0 * 64 + srow) * 64 + ((sunit ^ (srow & 7)) * 8);
    gload_lds16(g, kbuf[c0 & 1] + wave * 2048);
    gload_lds16(g + 8 * 64, kbuf[c0 & 1] + wave * 2048 + 1024);
  }
  __syncthreads();

  for (int c = c0; c < 8; ++c) {
    int cb = n0 + c * 64;
    // stage V(c)
    {
      int d = srow;
      const unsigned short* g = vb + (size_t)d * NTOK + cb + ((sunit ^ (d & 7)) * 8);
      gload_lds16(g, vbuf + wave * 2048);
      gload_lds16(g + (size_t)8 * NTOK, vbuf + wave * 2048 + 1024);
    }
    // stage K(c+1)
    if (c < 7) {
      const unsigned short* g = kb + (size_t)(cb + 64 + srow) * 64 + ((sunit ^ (srow & 7)) * 8);
      gload_lds16(g, kbuf[(c + 1) & 1] + wave * 2048);
      gload_lds16(g + 8 * 64, kbuf[(c + 1) & 1] + wave * 2048 + 1024);
    }

    // QK^T (swapped): S^T tiles, 64 keys x 32 q
    f32x16 s[2] = {{}, {}};
    const char* kl = kbuf[c & 1];
#pragma unroll
    for (int kt = 0; kt < 2; kt++) {
#pragma unroll
      for (int dht = 0; dht < 4; dht++) {
        int row = kt * 32 + l31;
        int unit = (dht * 2 + hi) ^ (row & 7);
        s8 kf = *(const s8*)(kl + row * 128 + unit * 16);
        s[kt] = __builtin_amdgcn_mfma_f32_32x32x16_bf16(kf, qf[dht], s[kt], 0, 0, 0);
      }
    }

    // masked exp (no max-sub) + denominator + pack to bf16 pairs
    unsigned P0[2][4], P1[2][4];
#pragma unroll
    for (int kt = 0; kt < 2; kt++) {
#pragma unroll
      for (int r = 0; r < 16; r++) {
        int j = c * 64 + kt * 32 + (r & 3) + 8 * (r >> 2) + hi * 4;  // key idx in 2-window frame
        float e = (j <= qw + 256) ? __expf(s[kt][r] * 0.125f) : 0.f;
        s[kt][r] = e;
        dsum += e;
      }
#pragma unroll
      for (int j2 = 0; j2 < 4; j2++) {
        P0[kt][j2] = pk2(s[kt][j2 * 4 + 0], s[kt][j2 * 4 + 1]);
        P1[kt][j2] = pk2(s[kt][j2 * 4 + 2], s[kt][j2 * 4 + 3]);
      }
    }

    __syncthreads();   // V(c) staged (drains K(c+1) too)

    // PV (swapped): O^T += V^T(chunk) . P^T(chunk)
#pragma unroll
    for (int tt = 0; tt < 4; tt++) {
      int kt = tt >> 1, ss = tt & 1;
      unsigned a = P0[kt][2 * ss], b = P1[kt][2 * ss];
      unsigned cx = P0[kt][2 * ss + 1], dx = P1[kt][2 * ss + 1];
      asm volatile("v_permlane32_swap_b32 %0, %1" : "+v"(a), "+v"(cx));
      asm volatile("v_permlane32_swap_b32 %0, %1" : "+v"(b), "+v"(dx));
      s8 pf = mk_s8(a, b, cx, dx);
      {
        int row = l31;
        int unit = (tt * 2 + hi) ^ (row & 7);
        s8 vf = *(const s8*)(vbuf + row * 128 + unit * 16);
        o0 = __builtin_amdgcn_mfma_f32_32x32x16_bf16(vf, pf, o0, 0, 0, 0);
      }
      {
        int row = 32 + l31;
        int unit = (tt * 2 + hi) ^ (row & 7);
        s8 vf = *(const s8*)(vbuf + row * 128 + unit * 16);
        o1 = __builtin_amdgcn_mfma_f32_32x32x16_bf16(vf, pf, o1, 0, 0, 0);
      }
    }
    __syncthreads();   // LDS consumed; next iter may overwrite
  }

  dsum += __shfl_xor(dsum, 32);
  float inv = 1.f / dsum;

  // O^T: lane col = q (l31), rows d = (r&3) + 8*(r>>2) + 4*hi (+32 for o1)
  unsigned short* orow = ao + (size_t)qn * INNER_ + h * 64;
#pragma unroll
  for (int g = 0; g < 4; g++) {
    us4 st0, st1;
#pragma unroll
    for (int rr = 0; rr < 4; rr++) {
      st0[rr] = f2b(o0[g * 4 + rr] * inv);
      st1[rr] = f2b(o1[g * 4 + rr] * inv);
    }
    *(us4*)(orow + g * 8 + hi * 4) = st0;
    *(us4*)(orow + 32 + g * 8 + hi * 4) = st1;
  }
}

// ---------------------------------------------------------------------------
extern "C" void kernel_launch(void* const* d_in, const int* in_sizes, int n_in,
                              void* d_out, int out_size, void* d_ws, size_t ws_size,
                              hipStream_t stream) {
  const float* x     = (const float*)d_in[0];
  const float* sin_  = (const float*)d_in[1];
  const float* cos_  = (const float*)d_in[2];
  const float* gamma = (const float*)d_in[3];
  const float* beta  = (const float*)d_in[4];
  const float* w_qkv = (const float*)d_in[5];
  const float* w_out = (const float*)d_in[6];
  const float* b_out = (const float*)d_in[7];

  // ws layout (bytes). total needed = 205,520,896 (~196 MiB)
  char* ws = (char*)d_ws;
  const size_t OFF_WQT = 0;                    // 1536*1024*2 = 3,145,728
  const size_t OFF_WOT = 3145728;              // 1024*512*2  = 1,048,576
  const size_t OFF_XS  = 4194304;              // 32768*1024*2 = 67,108,864
  const size_t OFF_QKV = 71303168;             // 32768*1536*2 = 100,663,296
  const size_t OFF_VT  = 171966464;            // 8*64*32768*2 = 33,554,432
  const size_t NEEDED  = 205520896;
  if (ws_size < NEEDED) return;  // fail loudly (output stays poisoned)

  unsigned short* wqT = (unsigned short*)(ws + OFF_WQT);
  unsigned short* woT = (unsigned short*)(ws + OFF_WOT);
  unsigned short* xs  = (unsigned short*)(ws + OFF_XS);
  unsigned short* qkv = (unsigned short*)(ws + OFF_QKV);
  unsigned short* vt  = (unsigned short*)(ws + OFF_VT);
  unsigned short* qh  = xs;                                   // reuse xs after gemm1
  unsigned short* kh  = (unsigned short*)(ws + OFF_XS + 33554432);
  unsigned short* ao  = qkv;                                  // reuse qkv after rotary

  transpose_f32_bf16<<<dim3(1536 / 32, 1024 / 32), dim3(32, 8), 0, stream>>>(w_qkv, wqT, 1024, 1536);
  transpose_f32_bf16<<<dim3(1024 / 32, 512 / 32), dim3(32, 8), 0, stream>>>(w_out, woT, 512, 1024);
  ln_shift<<<NTOK, 256, 0, stream>>>(x, gamma, beta, xs);
  gemm_nt<false><<<dim3(1536 / 128, NTOK / 128), 256, 0, stream>>>(xs, wqT, qkv, nullptr, NTOK, 1536, 1024);
  rotary_qk<<<(NTOK * 128) / 256, 256, 0, stream>>>(qkv, sin_, cos_, qh, kh);
  rotary_vT<<<dim3(NTOK / 64, HEADS_), 256, 0, stream>>>(qkv, sin_, cos_, vt);
  attn_kernel<<<dim3(2, NWIN_, HEADS_), 256, 0, stream>>>(qh, kh, vt, ao);
  gemm_nt<true><<<dim3(1024 / 128, NTOK / 128), 256, 0, stream>>>(ao, woT, (void*)d_out, b_out, NTOK, 1024, 512);
}

// Round 5
// 354.299 us; speedup vs baseline: 2.1075x; 1.1089x over previous
//
#include <hip/hip_runtime.h>

typedef __attribute__((ext_vector_type(4))) unsigned short us4;
typedef __attribute__((ext_vector_type(8))) unsigned short us8;
typedef __attribute__((ext_vector_type(8))) short s8;      // MFMA A/B fragment (8 bf16)
typedef __attribute__((ext_vector_type(4))) float f32x4;   // 16x16 MFMA acc / float4
typedef __attribute__((ext_vector_type(16))) float f32x16; // 32x32 MFMA acc

#define NTOK 32768
#define DIM_ 1024
#define HEADS_ 8
#define DH_ 64
#define WS_ 256
#define NWIN_ 128
#define INNER_ 512

__device__ __forceinline__ float b2f(unsigned short u) {
  union { unsigned u; float f; } x; x.u = ((unsigned)u) << 16; return x.f;
}
__device__ __forceinline__ unsigned short f2b(float f) {
  union { float f; unsigned u; } x; x.f = f;
  unsigned r = x.u + 0x7FFFu + ((x.u >> 16) & 1u);  // RNE
  return (unsigned short)(r >> 16);
}
__device__ __forceinline__ unsigned pk2(float a, float b) {
  return (unsigned)f2b(a) | ((unsigned)f2b(b) << 16);
}
__device__ __forceinline__ s8 mk_s8(unsigned w0, unsigned w1, unsigned w2, unsigned w3) {
  union { unsigned u[4]; s8 v; } x;
  x.u[0] = w0; x.u[1] = w1; x.u[2] = w2; x.u[3] = w3;
  return x.v;
}

// global -> LDS direct DMA, 16B per lane. LDS dest = wave-uniform base + lane*16.
__device__ __forceinline__ void gload_lds16(const unsigned short* g, void* l) {
  __builtin_amdgcn_global_load_lds((const __attribute__((address_space(1))) void*)g,
                                   (__attribute__((address_space(3))) void*)l, 16, 0, 0);
}

// ---------------------------------------------------------------------------
// LayerNorm (f32 in) + half-row shift -> bf16 xs.
// ---------------------------------------------------------------------------
__global__ __launch_bounds__(256) void ln_shift(const float* __restrict__ x,
                                                const float* __restrict__ gamma,
                                                const float* __restrict__ beta,
                                                unsigned short* __restrict__ xs) {
  int row = blockIdx.x;
  int t = threadIdx.x;
  f32x4 v = ((const f32x4*)(x + (size_t)row * DIM_))[t];
  float sum = 0.f, ss = 0.f;
#pragma unroll
  for (int j = 0; j < 4; j++) { sum += v[j]; ss += v[j] * v[j]; }
#pragma unroll
  for (int off = 32; off >= 1; off >>= 1) {
    sum += __shfl_xor(sum, off);
    ss  += __shfl_xor(ss, off);
  }
  __shared__ float red[2][4];
  int wave = t >> 6, l = t & 63;
  if (l == 0) { red[0][wave] = sum; red[1][wave] = ss; }
  __syncthreads();
  sum = red[0][0] + red[0][1] + red[0][2] + red[0][3];
  ss  = red[1][0] + red[1][1] + red[1][2] + red[1][3];
  float mu = sum * (1.0f / DIM_);
  float var = ss * (1.0f / DIM_) - mu * mu;
  float rs = rsqrtf(var + 1e-5f);
  f32x4 g = ((const f32x4*)gamma)[t];
  f32x4 bb = ((const f32x4*)beta)[t];
  us4 o;
#pragma unroll
  for (int j = 0; j < 4; j++) o[j] = f2b((v[j] - mu) * rs * g[j] + bb[j]);
  int c0 = t * 4;
  if (c0 >= 512) {
    *(us4*)(xs + (size_t)row * DIM_ + c0) = o;
  } else {
    if (row + 1 < NTOK) *(us4*)(xs + (size_t)(row + 1) * DIM_ + c0) = o;
    if (row == 0) { us4 z = {0, 0, 0, 0}; *(us4*)(xs + c0) = z; }
  }
}

// ---------------------------------------------------------------------------
// f32 (R,C) -> bf16 (C,R) transpose; R,C multiples of 32. block (32,8)
// ---------------------------------------------------------------------------
__global__ __launch_bounds__(256) void transpose_f32_bf16(const float* __restrict__ in,
                                                          unsigned short* __restrict__ out,
                                                          int R, int C) {
  __shared__ unsigned short tile[32][33];
  int bx = blockIdx.x * 32, by = blockIdx.y * 32;
  int tx = threadIdx.x, ty = threadIdx.y;
#pragma unroll
  for (int i = 0; i < 32; i += 8) tile[ty + i][tx] = f2b(in[(size_t)(by + ty + i) * C + bx + tx]);
  __syncthreads();
#pragma unroll
  for (int i = 0; i < 32; i += 8) out[(size_t)(bx + ty + i) * R + by + tx] = tile[tx][ty + i];
}

// ---------------------------------------------------------------------------
// Pipelined NT GEMM: C[M,N] = A[M,K] @ Bt[N,K]^T (+bias), bf16 in, f32 acc.
// 256x256 tile, BK=32, 512 thr (8 waves 2Mx4N, wave tile 128x64).
// 4-slot LDS rotation (128 KiB), global_load_lds w16 staged 3 K-tiles ahead,
// counted s_waitcnt vmcnt(10) (never 0 in main loop), 2 phases x 16 MFMA.
// ---------------------------------------------------------------------------
template <bool F32OUT>
__global__ __launch_bounds__(512, 2) void gemm_nt_pipe(const unsigned short* __restrict__ A,
                                                       const unsigned short* __restrict__ Bt,
                                                       void* __restrict__ Cv,
                                                       const float* __restrict__ bias,
                                                       int M, int N, int K) {
  __shared__ __align__(16) char lds[131072];   // slot s: A at s*32768, B at +16384
  int t = threadIdx.x;
  int l = t & 63, lg = l >> 4, ll = l & 15;
  int wave = t >> 6;
  int wm = wave >> 2, wn = wave & 3;

  // XCD-bijective flat block swizzle (nwg % 8 == 0 for all our grids)
  int nbx = gridDim.x;
  int nwg = nbx * gridDim.y;
  int flat = blockIdx.y * nbx + blockIdx.x;
  int swz = (flat & 7) * (nwg >> 3) + (flat >> 3);
  int m0 = (swz / nbx) * 256, n0 = (swz % nbx) * 256;

  const f32x4 fz = {0.f, 0.f, 0.f, 0.f};
  f32x4 acc[8][4];
#pragma unroll
  for (int m = 0; m < 8; m++)
#pragma unroll
    for (int n = 0; n < 4; n++) acc[m][n] = fz;

  // staging geometry: 512 thr x 16B = 8KB = 128 rows x 64B per issue
  int srow = t >> 2;                           // 0..127
  int sunit = (t & 3) ^ ((t >> 3) & 3);        // pre-swizzled source 16B-unit
  const unsigned short* gA = A + (size_t)(m0 + srow) * K + sunit * 8;
  const unsigned short* gB = Bt + (size_t)(n0 + srow) * K + sunit * 8;
  char* myA = lds + wave * 1024;               // + slot*32768 + j*8192
  char* myB = lds + 16384 + wave * 1024;

  int fsw = (ll >> 1) & 3;                     // fragment-read swizzle key
  int nk = K >> 5;

  // prologue: stage K-tiles 0,1,2 (12 issues, oldest-first)
#pragma unroll
  for (int s = 0; s < 3; s++) {
    gload_lds16(gA + s * 32, myA + s * 32768);
    gload_lds16(gA + s * 32 + (size_t)128 * K, myA + s * 32768 + 8192);
    gload_lds16(gB + s * 32, myB + s * 32768);
    gload_lds16(gB + s * 32 + (size_t)128 * K, myB + s * 32768 + 8192);
  }

  for (int kt = 0; kt < nk - 3; ++kt) {
    const char* sa = lds + (kt & 3) * 32768;
    const char* sb = sa + 16384;
    int pslot = ((kt + 3) & 3) * 32768;
    // ---- phase A: stage A(kt+3); compute m0-3 x n0-3 ----
    gload_lds16(gA + (kt + 3) * 32, myA + pslot);
    gload_lds16(gA + (kt + 3) * 32 + (size_t)128 * K, myA + pslot + 8192);
    asm volatile("s_waitcnt vmcnt(10)" ::: "memory");  // oldest 4 (K-tile kt) landed
    __builtin_amdgcn_s_barrier();
    __builtin_amdgcn_sched_barrier(0);
    s8 af[4], bf[4];
#pragma unroll
    for (int n = 0; n < 4; n++) {
      int r = wn * 64 + n * 16 + ll;
      bf[n] = *(const s8*)(sb + r * 64 + ((lg ^ fsw) << 4));
    }
#pragma unroll
    for (int m = 0; m < 4; m++) {
      int r = wm * 128 + m * 16 + ll;
      af[m] = *(const s8*)(sa + r * 64 + ((lg ^ fsw) << 4));
    }
    __builtin_amdgcn_s_setprio(1);
#pragma unroll
    for (int m = 0; m < 4; m++)
#pragma unroll
      for (int n = 0; n < 4; n++)
        acc[m][n] = __builtin_amdgcn_mfma_f32_16x16x32_bf16(af[m], bf[n], acc[m][n], 0, 0, 0);
    __builtin_amdgcn_s_setprio(0);
    // ---- phase B: stage B(kt+3); compute m4-7 x n0-3 ----
    gload_lds16(gB + (kt + 3) * 32, myB + pslot);
    gload_lds16(gB + (kt + 3) * 32 + (size_t)128 * K, myB + pslot + 8192);
    s8 af2[4];
#pragma unroll
    for (int m = 0; m < 4; m++) {
      int r = wm * 128 + 64 + m * 16 + ll;
      af2[m] = *(const s8*)(sa + r * 64 + ((lg ^ fsw) << 4));
    }
    __builtin_amdgcn_s_setprio(1);
#pragma unroll
    for (int m = 0; m < 4; m++)
#pragma unroll
      for (int n = 0; n < 4; n++)
        acc[m + 4][n] = __builtin_amdgcn_mfma_f32_16x16x32_bf16(af2[m], bf[n], acc[m + 4][n], 0, 0, 0);
    __builtin_amdgcn_s_setprio(0);
    __builtin_amdgcn_sched_barrier(0);
    __builtin_amdgcn_s_barrier();   // slot kt readers done -> reusable
  }

  // epilogue: drain all staging, compute last 3 K-tiles (no more writes)
  asm volatile("s_waitcnt vmcnt(0)" ::: "memory");
  __builtin_amdgcn_s_barrier();
  __builtin_amdgcn_sched_barrier(0);
  for (int kt = nk - 3; kt < nk; ++kt) {
    const char* sa = lds + (kt & 3) * 32768;
    const char* sb = sa + 16384;
    s8 af[4], bf[4], af2[4];
#pragma unroll
    for (int n = 0; n < 4; n++) {
      int r = wn * 64 + n * 16 + ll;
      bf[n] = *(const s8*)(sb + r * 64 + ((lg ^ fsw) << 4));
    }
#pragma unroll
    for (int m = 0; m < 4; m++) {
      int r = wm * 128 + m * 16 + ll;
      af[m] = *(const s8*)(sa + r * 64 + ((lg ^ fsw) << 4));
    }
#pragma unroll
    for (int m = 0; m < 4; m++) {
      int r = wm * 128 + 64 + m * 16 + ll;
      af2[m] = *(const s8*)(sa + r * 64 + ((lg ^ fsw) << 4));
    }
#pragma unroll
    for (int m = 0; m < 4; m++)
#pragma unroll
      for (int n = 0; n < 4; n++)
        acc[m][n] = __builtin_amdgcn_mfma_f32_16x16x32_bf16(af[m], bf[n], acc[m][n], 0, 0, 0);
#pragma unroll
    for (int m = 0; m < 4; m++)
#pragma unroll
      for (int n = 0; n < 4; n++)
        acc[m + 4][n] = __builtin_amdgcn_mfma_f32_16x16x32_bf16(af2[m], bf[n], acc[m + 4][n], 0, 0, 0);
  }

  // C write
#pragma unroll
  for (int n = 0; n < 4; n++) {
    int col = n0 + wn * 64 + n * 16 + ll;
    float bs = bias ? bias[col] : 0.0f;
#pragma unroll
    for (int m = 0; m < 8; m++) {
#pragma unroll
      for (int r = 0; r < 4; r++) {
        int row = m0 + wm * 128 + m * 16 + lg * 4 + r;
        if (F32OUT) ((float*)Cv)[(size_t)row * N + col] = acc[m][n][r] + bs;
        else ((unsigned short*)Cv)[(size_t)row * N + col] = f2b(acc[m][n][r] + bs);
      }
    }
  }
}

// ---------------------------------------------------------------------------
// RoPE on q,k thirds of qkv (bf16) with f32 sin/cos -> head-major (8, N, 64)
// ---------------------------------------------------------------------------
__global__ __launch_bounds__(256) void rotary_qk(const unsigned short* __restrict__ qkv,
                                                 const float* __restrict__ sn,
                                                 const float* __restrict__ cs,
                                                 unsigned short* __restrict__ qh,
                                                 unsigned short* __restrict__ kh) {
  int gid = blockIdx.x * 256 + threadIdx.x;
  int n = gid >> 7;
  int col = (gid & 127) * 8;
  int d = col & 63;
  us8 v = *(const us8*)(qkv + (size_t)n * 1536 + col);
  float se[8], ce[8];
  *(f32x4*)se = *(const f32x4*)(sn + (size_t)n * 64 + d);
  *(f32x4*)(se + 4) = *(const f32x4*)(sn + (size_t)n * 64 + d + 4);
  *(f32x4*)ce = *(const f32x4*)(cs + (size_t)n * 64 + d);
  *(f32x4*)(ce + 4) = *(const f32x4*)(cs + (size_t)n * 64 + d + 4);
  us8 o;
#pragma unroll
  for (int p = 0; p < 4; p++) {
    float v0 = b2f(v[2 * p]), v1 = b2f(v[2 * p + 1]);
    o[2 * p]     = f2b(v0 * ce[2 * p] - v1 * se[2 * p]);
    o[2 * p + 1] = f2b(v1 * ce[2 * p + 1] + v0 * se[2 * p + 1]);
  }
  int third = col >> 9;
  int cw = col & 511;
  int h = cw >> 6;
  unsigned short* dst = third ? kh : qh;
  *(us8*)(dst + ((size_t)h * NTOK + n) * 64 + (cw & 63)) = o;
}

// ---------------------------------------------------------------------------
// RoPE on v third + transpose -> v_t (8, 64, N). block = 64n x 64d tile.
// ---------------------------------------------------------------------------
__global__ __launch_bounds__(256) void rotary_vT(const unsigned short* __restrict__ qkv,
                                                 const float* __restrict__ sn,
                                                 const float* __restrict__ cs,
                                                 unsigned short* __restrict__ vt) {
  __shared__ unsigned short tile[64][72];
  int nt = blockIdx.x, h = blockIdx.y;
  int t = threadIdx.x;
  int i = t >> 2;
  int cc = (t & 3) * 16;
  int n = nt * 64 + i;
  const unsigned short* src = qkv + (size_t)n * 1536 + 1024 + h * 64 + cc;
  us8 v0 = *(const us8*)src;
  us8 v1 = *(const us8*)(src + 8);
  float se[16], ce[16];
#pragma unroll
  for (int q = 0; q < 4; q++) {
    *(f32x4*)(se + 4 * q) = *(const f32x4*)(sn + (size_t)n * 64 + cc + 4 * q);
    *(f32x4*)(ce + 4 * q) = *(const f32x4*)(cs + (size_t)n * 64 + cc + 4 * q);
  }
#pragma unroll
  for (int p = 0; p < 4; p++) {
    float a0 = b2f(v0[2 * p]), a1 = b2f(v0[2 * p + 1]);
    tile[i][cc + 2 * p]     = f2b(a0 * ce[2 * p] - a1 * se[2 * p]);
    tile[i][cc + 2 * p + 1] = f2b(a1 * ce[2 * p + 1] + a0 * se[2 * p + 1]);
    float b0 = b2f(v1[2 * p]), b1 = b2f(v1[2 * p + 1]);
    tile[i][cc + 8 + 2 * p]     = f2b(b0 * ce[8 + 2 * p] - b1 * se[8 + 2 * p]);
    tile[i][cc + 8 + 2 * p + 1] = f2b(b1 * ce[8 + 2 * p + 1] + b0 * se[8 + 2 * p + 1]);
  }
  __syncthreads();
  int dd = t >> 2;
  int nc = (t & 3) * 16;
  us8 r0, r1;
#pragma unroll
  for (int j = 0; j < 8; j++) { r0[j] = tile[nc + j][dd]; r1[j] = tile[nc + 8 + j][dd]; }
  unsigned short* dst = vt + ((size_t)h * 64 + dd) * NTOK + (size_t)nt * 64 + nc;
  *(us8*)dst = r0;
  *(us8*)(dst + 8) = r1;
}

// ---------------------------------------------------------------------------
// Windowed lookback attention, v3: 32x32 MFMA, swapped operands.
// block = (half, window, head), 4 waves x 32 q-rows. 8 chunks of 64 keys.
// ---------------------------------------------------------------------------
__global__ __launch_bounds__(256, 4) void attn_kernel(const unsigned short* __restrict__ qh,
                                                      const unsigned short* __restrict__ kh,
                                                      const unsigned short* __restrict__ vt,
                                                      unsigned short* __restrict__ ao) {
  __shared__ char kbuf[2][8192];   // 64 keys x 128B, unit-swizzled by (row&7)
  __shared__ char vbuf[8192];      // 64 d x 128B (64 keys), unit-swizzled by (d&7)
  int half = blockIdx.x, w = blockIdx.y, h = blockIdx.z;
  int t = threadIdx.x;
  int wave = t >> 6, l = t & 63;
  int l31 = l & 31, hi = l >> 5;
  const unsigned short* qb = qh + (size_t)h * NTOK * 64;
  const unsigned short* kb = kh + (size_t)h * NTOK * 64;
  const unsigned short* vb = vt + (size_t)h * 64 * NTOK;

  int qw = half * 128 + wave * 32 + l31;   // q within window
  int qn = w * 256 + qw;                   // global token
  s8 qf[4];
#pragma unroll
  for (int dht = 0; dht < 4; dht++)
    qf[dht] = *(const s8*)(qb + (size_t)qn * 64 + dht * 16 + hi * 8);

  f32x16 o0 = {}, o1 = {};
  float dsum = (w == 0) ? 128.f : 0.f;     // 256 zero-keys -> exp(0)=1, split across hi halves
  int n0 = w * 256 - 256;
  int c0 = (w == 0) ? 4 : 0;

  int srow = wave * 16 + (l >> 3);
  int sunit = l & 7;

  // prologue: stage K(c0)
  {
    const unsigned short* g = kb + (size_t)(n0 + c0 * 64 + srow) * 64 + ((sunit ^ (srow & 7)) * 8);
    gload_lds16(g, kbuf[c0 & 1] + wave * 2048);
    gload_lds16(g + 8 * 64, kbuf[c0 & 1] + wave * 2048 + 1024);
  }
  __syncthreads();

  for (int c = c0; c < 8; ++c) {
    int cb = n0 + c * 64;
    // stage V(c)
    {
      int d = srow;
      const unsigned short* g = vb + (size_t)d * NTOK + cb + ((sunit ^ (d & 7)) * 8);
      gload_lds16(g, vbuf + wave * 2048);
      gload_lds16(g + (size_t)8 * NTOK, vbuf + wave * 2048 + 1024);
    }
    // stage K(c+1)
    if (c < 7) {
      const unsigned short* g = kb + (size_t)(cb + 64 + srow) * 64 + ((sunit ^ (srow & 7)) * 8);
      gload_lds16(g, kbuf[(c + 1) & 1] + wave * 2048);
      gload_lds16(g + 8 * 64, kbuf[(c + 1) & 1] + wave * 2048 + 1024);
    }

    // QK^T (swapped): S^T tiles, 64 keys x 32 q
    f32x16 s[2] = {{}, {}};
    const char* kl = kbuf[c & 1];
#pragma unroll
    for (int kt = 0; kt < 2; kt++) {
#pragma unroll
      for (int dht = 0; dht < 4; dht++) {
        int row = kt * 32 + l31;
        int unit = (dht * 2 + hi) ^ (row & 7);
        s8 kf = *(const s8*)(kl + row * 128 + unit * 16);
        s[kt] = __builtin_amdgcn_mfma_f32_32x32x16_bf16(kf, qf[dht], s[kt], 0, 0, 0);
      }
    }

    // masked exp (no max-sub) + denominator + pack to bf16 pairs
    unsigned P0[2][4], P1[2][4];
#pragma unroll
    for (int kt = 0; kt < 2; kt++) {
#pragma unroll
      for (int r = 0; r < 16; r++) {
        int j = c * 64 + kt * 32 + (r & 3) + 8 * (r >> 2) + hi * 4;
        float e = (j <= qw + 256) ? __expf(s[kt][r] * 0.125f) : 0.f;
        s[kt][r] = e;
        dsum += e;
      }
#pragma unroll
      for (int j2 = 0; j2 < 4; j2++) {
        P0[kt][j2] = pk2(s[kt][j2 * 4 + 0], s[kt][j2 * 4 + 1]);
        P1[kt][j2] = pk2(s[kt][j2 * 4 + 2], s[kt][j2 * 4 + 3]);
      }
    }

    __syncthreads();   // V(c) staged (drains K(c+1) too)

    // PV (swapped): O^T += V^T(chunk) . P^T(chunk)
#pragma unroll
    for (int tt = 0; tt < 4; tt++) {
      int kt = tt >> 1, ss = tt & 1;
      unsigned a = P0[kt][2 * ss], b = P1[kt][2 * ss];
      unsigned cx = P0[kt][2 * ss + 1], dx = P1[kt][2 * ss + 1];
      asm volatile("v_permlane32_swap_b32 %0, %1" : "+v"(a), "+v"(cx));
      asm volatile("v_permlane32_swap_b32 %0, %1" : "+v"(b), "+v"(dx));
      s8 pf = mk_s8(a, b, cx, dx);
      {
        int row = l31;
        int unit = (tt * 2 + hi) ^ (row & 7);
        s8 vf = *(const s8*)(vbuf + row * 128 + unit * 16);
        o0 = __builtin_amdgcn_mfma_f32_32x32x16_bf16(vf, pf, o0, 0, 0, 0);
      }
      {
        int row = 32 + l31;
        int unit = (tt * 2 + hi) ^ (row & 7);
        s8 vf = *(const s8*)(vbuf + row * 128 + unit * 16);
        o1 = __builtin_amdgcn_mfma_f32_32x32x16_bf16(vf, pf, o1, 0, 0, 0);
      }
    }
    __syncthreads();   // LDS consumed; next iter may overwrite
  }

  dsum += __shfl_xor(dsum, 32);
  float inv = 1.f / dsum;

  unsigned short* orow = ao + (size_t)qn * INNER_ + h * 64;
#pragma unroll
  for (int g = 0; g < 4; g++) {
    us4 st0, st1;
#pragma unroll
    for (int rr = 0; rr < 4; rr++) {
      st0[rr] = f2b(o0[g * 4 + rr] * inv);
      st1[rr] = f2b(o1[g * 4 + rr] * inv);
    }
    *(us4*)(orow + g * 8 + hi * 4) = st0;
    *(us4*)(orow + 32 + g * 8 + hi * 4) = st1;
  }
}

// ---------------------------------------------------------------------------
extern "C" void kernel_launch(void* const* d_in, const int* in_sizes, int n_in,
                              void* d_out, int out_size, void* d_ws, size_t ws_size,
                              hipStream_t stream) {
  const float* x     = (const float*)d_in[0];
  const float* sin_  = (const float*)d_in[1];
  const float* cos_  = (const float*)d_in[2];
  const float* gamma = (const float*)d_in[3];
  const float* beta  = (const float*)d_in[4];
  const float* w_qkv = (const float*)d_in[5];
  const float* w_out = (const float*)d_in[6];
  const float* b_out = (const float*)d_in[7];

  // ws layout (bytes). total needed = 205,520,896 (~196 MiB)
  char* ws = (char*)d_ws;
  const size_t OFF_WQT = 0;                    // 1536*1024*2 = 3,145,728
  const size_t OFF_WOT = 3145728;              // 1024*512*2  = 1,048,576
  const size_t OFF_XS  = 4194304;              // 32768*1024*2 = 67,108,864
  const size_t OFF_QKV = 71303168;             // 32768*1536*2 = 100,663,296
  const size_t OFF_VT  = 171966464;            // 8*64*32768*2 = 33,554,432
  const size_t NEEDED  = 205520896;
  if (ws_size < NEEDED) return;  // fail loudly (output stays poisoned)

  unsigned short* wqT = (unsigned short*)(ws + OFF_WQT);
  unsigned short* woT = (unsigned short*)(ws + OFF_WOT);
  unsigned short* xs  = (unsigned short*)(ws + OFF_XS);
  unsigned short* qkv = (unsigned short*)(ws + OFF_QKV);
  unsigned short* vt  = (unsigned short*)(ws + OFF_VT);
  unsigned short* qh  = xs;                                   // reuse xs after gemm1
  unsigned short* kh  = (unsigned short*)(ws + OFF_XS + 33554432);
  unsigned short* ao  = qkv;                                  // reuse qkv after rotary

  transpose_f32_bf16<<<dim3(1536 / 32, 1024 / 32), dim3(32, 8), 0, stream>>>(w_qkv, wqT, 1024, 1536);
  transpose_f32_bf16<<<dim3(1024 / 32, 512 / 32), dim3(32, 8), 0, stream>>>(w_out, woT, 512, 1024);
  ln_shift<<<NTOK, 256, 0, stream>>>(x, gamma, beta, xs);
  gemm_nt_pipe<false><<<dim3(1536 / 256, NTOK / 256), 512, 0, stream>>>(xs, wqT, qkv, nullptr, NTOK, 1536, 1024);
  rotary_qk<<<(NTOK * 128) / 256, 256, 0, stream>>>(qkv, sin_, cos_, qh, kh);
  rotary_vT<<<dim3(NTOK / 64, HEADS_), 256, 0, stream>>>(qkv, sin_, cos_, vt);
  attn_kernel<<<dim3(2, NWIN_, HEADS_), 256, 0, stream>>>(qh, kh, vt, ao);
  gemm_nt_pipe<true><<<dim3(1024 / 256, NTOK / 256), 512, 0, stream>>>(ao, woT, (void*)d_out, b_out, NTOK, 1024, 512);
}

// Round 6
// 342.871 us; speedup vs baseline: 2.1777x; 1.0333x over previous
//
#include <hip/hip_runtime.h>

typedef __attribute__((ext_vector_type(4))) unsigned short us4;
typedef __attribute__((ext_vector_type(8))) unsigned short us8;
typedef __attribute__((ext_vector_type(8))) short s8;      // MFMA A/B fragment (8 bf16)
typedef __attribute__((ext_vector_type(4))) float f32x4;   // 16x16 MFMA acc / float4
typedef __attribute__((ext_vector_type(16))) float f32x16; // 32x32 MFMA acc

#define NTOK 32768
#define DIM_ 1024
#define HEADS_ 8
#define DH_ 64
#define WS_ 256
#define NWIN_ 128
#define INNER_ 512

__device__ __forceinline__ float b2f(unsigned short u) {
  union { unsigned u; float f; } x; x.u = ((unsigned)u) << 16; return x.f;
}
__device__ __forceinline__ unsigned short f2b(float f) {
  union { float f; unsigned u; } x; x.f = f;
  unsigned r = x.u + 0x7FFFu + ((x.u >> 16) & 1u);  // RNE
  return (unsigned short)(r >> 16);
}
__device__ __forceinline__ unsigned pk2(float a, float b) {
  return (unsigned)f2b(a) | ((unsigned)f2b(b) << 16);
}
__device__ __forceinline__ s8 mk_s8(unsigned w0, unsigned w1, unsigned w2, unsigned w3) {
  union { unsigned u[4]; s8 v; } x;
  x.u[0] = w0; x.u[1] = w1; x.u[2] = w2; x.u[3] = w3;
  return x.v;
}

// global -> LDS direct DMA, 16B per lane. LDS dest = wave-uniform base + lane*16.
__device__ __forceinline__ void gload_lds16(const unsigned short* g, void* l) {
  __builtin_amdgcn_global_load_lds((const __attribute__((address_space(1))) void*)g,
                                   (__attribute__((address_space(3))) void*)l, 16, 0, 0);
}

// ---------------------------------------------------------------------------
// LayerNorm (f32 in) + half-row shift -> bf16 xs.
// ---------------------------------------------------------------------------
__global__ __launch_bounds__(256) void ln_shift(const float* __restrict__ x,
                                                const float* __restrict__ gamma,
                                                const float* __restrict__ beta,
                                                unsigned short* __restrict__ xs) {
  int row = blockIdx.x;
  int t = threadIdx.x;
  f32x4 v = ((const f32x4*)(x + (size_t)row * DIM_))[t];
  float sum = 0.f, ss = 0.f;
#pragma unroll
  for (int j = 0; j < 4; j++) { sum += v[j]; ss += v[j] * v[j]; }
#pragma unroll
  for (int off = 32; off >= 1; off >>= 1) {
    sum += __shfl_xor(sum, off);
    ss  += __shfl_xor(ss, off);
  }
  __shared__ float red[2][4];
  int wave = t >> 6, l = t & 63;
  if (l == 0) { red[0][wave] = sum; red[1][wave] = ss; }
  __syncthreads();
  sum = red[0][0] + red[0][1] + red[0][2] + red[0][3];
  ss  = red[1][0] + red[1][1] + red[1][2] + red[1][3];
  float mu = sum * (1.0f / DIM_);
  float var = ss * (1.0f / DIM_) - mu * mu;
  float rs = rsqrtf(var + 1e-5f);
  f32x4 g = ((const f32x4*)gamma)[t];
  f32x4 bb = ((const f32x4*)beta)[t];
  us4 o;
#pragma unroll
  for (int j = 0; j < 4; j++) o[j] = f2b((v[j] - mu) * rs * g[j] + bb[j]);
  int c0 = t * 4;
  if (c0 >= 512) {
    *(us4*)(xs + (size_t)row * DIM_ + c0) = o;
  } else {
    if (row + 1 < NTOK) *(us4*)(xs + (size_t)(row + 1) * DIM_ + c0) = o;
    if (row == 0) { us4 z = {0, 0, 0, 0}; *(us4*)(xs + c0) = z; }
  }
}

// ---------------------------------------------------------------------------
// f32 (R,C) -> bf16 (C,R) transpose; R,C multiples of 32. block (32,8)
// ---------------------------------------------------------------------------
__global__ __launch_bounds__(256) void transpose_f32_bf16(const float* __restrict__ in,
                                                          unsigned short* __restrict__ out,
                                                          int R, int C) {
  __shared__ unsigned short tile[32][33];
  int bx = blockIdx.x * 32, by = blockIdx.y * 32;
  int tx = threadIdx.x, ty = threadIdx.y;
#pragma unroll
  for (int i = 0; i < 32; i += 8) tile[ty + i][tx] = f2b(in[(size_t)(by + ty + i) * C + bx + tx]);
  __syncthreads();
#pragma unroll
  for (int i = 0; i < 32; i += 8) out[(size_t)(bx + ty + i) * R + by + tx] = tile[tx][ty + i];
}

// ---------------------------------------------------------------------------
// 8-phase-style pipelined NT GEMM: C[M,N] = A[M,K] @ Bt[N,K]^T (+bias).
// BM=BN=256, BK=64, 512 thr (8 waves 2Mx4N, wave tile 128x64).
// 2-slot LDS dbuf (128 KiB). Per K-tile: 4 phases x 16 MFMA, staging spread
// across phases, counted vmcnt(2) gate (retires exactly tile kt's 8 loads),
// barrier A (data ready) + barrier B (readers done -> slot reusable).
// LDS[r][u] = G[r][u^(r&7)] (u = 16B unit, 8 per 128B row).
// ---------------------------------------------------------------------------
template <bool F32OUT>
__global__ __launch_bounds__(512, 2) void gemm_nt_p8(const unsigned short* __restrict__ A,
                                                     const unsigned short* __restrict__ Bt,
                                                     void* __restrict__ Cv,
                                                     const float* __restrict__ bias,
                                                     int M, int N, int K) {
  __shared__ __align__(16) char lds[131072];   // slot s: A at s*65536, B at +32768
  int t = threadIdx.x;
  int l = t & 63, lg = l >> 4, ll = l & 15;
  int wave = t >> 6;
  int wm = wave >> 2, wn = wave & 3;

  // XCD-bijective flat block swizzle (nwg % 8 == 0 for all our grids)
  int nbx = gridDim.x;
  int nwg = nbx * gridDim.y;
  int flat = blockIdx.y * nbx + blockIdx.x;
  int swz = (flat & 7) * (nwg >> 3) + (flat >> 3);
  int m0 = (swz / nbx) * 256, n0 = (swz % nbx) * 256;

  const f32x4 fz = {0.f, 0.f, 0.f, 0.f};
  f32x4 acc[8][4];
#pragma unroll
  for (int m = 0; m < 8; m++)
#pragma unroll
    for (int n = 0; n < 4; n++) acc[m][n] = fz;

  // staging: issue j covers rows j*64 + (t>>3), unit (t&7)^(row&7); 8KB/issue
  int srow = t >> 3;                           // 0..63
  int sunit = (t & 7) ^ (srow & 7);            // pre-swizzled source 16B-unit
  const unsigned short* gA = A + (size_t)(m0 + srow) * K + sunit * 8;
  const unsigned short* gB = Bt + (size_t)(n0 + srow) * K + sunit * 8;
  int t16 = t * 16;
  int nk = K >> 6;

  // prologue: stage tile 0 into slot 0 (8 issues)
#pragma unroll
  for (int j = 0; j < 4; j++) {
    gload_lds16(gA + (size_t)(j * 64) * K, lds + j * 8192 + t16);
    gload_lds16(gB + (size_t)(j * 64) * K, lds + 32768 + j * 8192 + t16);
  }

  for (int kt = 0; kt < nk - 1; ++kt) {
    const char* sa = lds + (kt & 1) * 65536;
    const char* sb = sa + 32768;
    char* dA = lds + ((kt + 1) & 1) * 65536;
    char* dB = dA + 32768;
    const unsigned short* nA = gA + (kt + 1) * 64;
    const unsigned short* nB = gB + (kt + 1) * 64;

    // pre-gate: stage A j0,j1 of tile kt+1 (slot^1: its readers finished
    // before the previous iteration's barrier B)
    gload_lds16(nA, dA + t16);
    gload_lds16(nA + (size_t)64 * K, dA + 8192 + t16);
    asm volatile("s_waitcnt vmcnt(2)" ::: "memory");  // tile kt's 8 loads landed
    __builtin_amdgcn_sched_barrier(0);
    __builtin_amdgcn_s_barrier();                     // barrier A: data ready
    __builtin_amdgcn_sched_barrier(0);

    s8 bf[4];
#pragma unroll
    for (int p = 0; p < 4; ++p) {
      const int qm = p & 1, kk = p >> 1;
      s8 af[4];
#pragma unroll
      for (int m = 0; m < 4; m++) {
        int r = wm * 128 + qm * 64 + m * 16 + ll;
        af[m] = *(const s8*)(sa + r * 128 + (((kk * 4 + lg) ^ (r & 7)) << 4));
      }
      if (qm == 0) {
#pragma unroll
        for (int n = 0; n < 4; n++) {
          int r = wn * 64 + n * 16 + ll;
          bf[n] = *(const s8*)(sb + r * 128 + (((kk * 4 + lg) ^ (r & 7)) << 4));
        }
      }
      if (p == 0) {
        gload_lds16(nA + (size_t)128 * K, dA + 16384 + t16);
        gload_lds16(nA + (size_t)192 * K, dA + 24576 + t16);
      } else if (p == 1) {
        gload_lds16(nB, dB + t16);
        gload_lds16(nB + (size_t)64 * K, dB + 8192 + t16);
      } else if (p == 2) {
        gload_lds16(nB + (size_t)128 * K, dB + 16384 + t16);
        gload_lds16(nB + (size_t)192 * K, dB + 24576 + t16);
      }
      __builtin_amdgcn_s_setprio(1);
#pragma unroll
      for (int m = 0; m < 4; m++)
#pragma unroll
        for (int n = 0; n < 4; n++)
          acc[qm * 4 + m][n] =
              __builtin_amdgcn_mfma_f32_16x16x32_bf16(af[m], bf[n], acc[qm * 4 + m][n], 0, 0, 0);
      __builtin_amdgcn_s_setprio(0);
    }
    __builtin_amdgcn_sched_barrier(0);
    __builtin_amdgcn_s_barrier();   // barrier B: all reads of slot kt done
  }

  // final K-tile: no staging
  {
    int kt = nk - 1;
    const char* sa = lds + (kt & 1) * 65536;
    const char* sb = sa + 32768;
    asm volatile("s_waitcnt vmcnt(0)" ::: "memory");
    __builtin_amdgcn_sched_barrier(0);
    __builtin_amdgcn_s_barrier();
    __builtin_amdgcn_sched_barrier(0);
    s8 bf[4];
#pragma unroll
    for (int p = 0; p < 4; ++p) {
      const int qm = p & 1, kk = p >> 1;
      s8 af[4];
#pragma unroll
      for (int m = 0; m < 4; m++) {
        int r = wm * 128 + qm * 64 + m * 16 + ll;
        af[m] = *(const s8*)(sa + r * 128 + (((kk * 4 + lg) ^ (r & 7)) << 4));
      }
      if (qm == 0) {
#pragma unroll
        for (int n = 0; n < 4; n++) {
          int r = wn * 64 + n * 16 + ll;
          bf[n] = *(const s8*)(sb + r * 128 + (((kk * 4 + lg) ^ (r & 7)) << 4));
        }
      }
#pragma unroll
      for (int m = 0; m < 4; m++)
#pragma unroll
        for (int n = 0; n < 4; n++)
          acc[qm * 4 + m][n] =
              __builtin_amdgcn_mfma_f32_16x16x32_bf16(af[m], bf[n], acc[qm * 4 + m][n], 0, 0, 0);
    }
  }

  // C write
#pragma unroll
  for (int n = 0; n < 4; n++) {
    int col = n0 + wn * 64 + n * 16 + ll;
    float bs = bias ? bias[col] : 0.0f;
#pragma unroll
    for (int m = 0; m < 8; m++) {
#pragma unroll
      for (int r = 0; r < 4; r++) {
        int row = m0 + wm * 128 + m * 16 + lg * 4 + r;
        if (F32OUT) ((float*)Cv)[(size_t)row * N + col] = acc[m][n][r] + bs;
        else ((unsigned short*)Cv)[(size_t)row * N + col] = f2b(acc[m][n][r] + bs);
      }
    }
  }
}

// ---------------------------------------------------------------------------
// RoPE on q,k thirds of qkv (bf16) with f32 sin/cos -> head-major (8, N, 64)
// ---------------------------------------------------------------------------
__global__ __launch_bounds__(256) void rotary_qk(const unsigned short* __restrict__ qkv,
                                                 const float* __restrict__ sn,
                                                 const float* __restrict__ cs,
                                                 unsigned short* __restrict__ qh,
                                                 unsigned short* __restrict__ kh) {
  int gid = blockIdx.x * 256 + threadIdx.x;
  int n = gid >> 7;
  int col = (gid & 127) * 8;
  int d = col & 63;
  us8 v = *(const us8*)(qkv + (size_t)n * 1536 + col);
  float se[8], ce[8];
  *(f32x4*)se = *(const f32x4*)(sn + (size_t)n * 64 + d);
  *(f32x4*)(se + 4) = *(const f32x4*)(sn + (size_t)n * 64 + d + 4);
  *(f32x4*)ce = *(const f32x4*)(cs + (size_t)n * 64 + d);
  *(f32x4*)(ce + 4) = *(const f32x4*)(cs + (size_t)n * 64 + d + 4);
  us8 o;
#pragma unroll
  for (int p = 0; p < 4; p++) {
    float v0 = b2f(v[2 * p]), v1 = b2f(v[2 * p + 1]);
    o[2 * p]     = f2b(v0 * ce[2 * p] - v1 * se[2 * p]);
    o[2 * p + 1] = f2b(v1 * ce[2 * p + 1] + v0 * se[2 * p + 1]);
  }
  int third = col >> 9;
  int cw = col & 511;
  int h = cw >> 6;
  unsigned short* dst = third ? kh : qh;
  *(us8*)(dst + ((size_t)h * NTOK + n) * 64 + (cw & 63)) = o;
}

// ---------------------------------------------------------------------------
// RoPE on v third + transpose -> v_t (8, 64, N). block = 64n x 64d tile.
// ---------------------------------------------------------------------------
__global__ __launch_bounds__(256) void rotary_vT(const unsigned short* __restrict__ qkv,
                                                 const float* __restrict__ sn,
                                                 const float* __restrict__ cs,
                                                 unsigned short* __restrict__ vt) {
  __shared__ unsigned short tile[64][72];
  int nt = blockIdx.x, h = blockIdx.y;
  int t = threadIdx.x;
  int i = t >> 2;
  int cc = (t & 3) * 16;
  int n = nt * 64 + i;
  const unsigned short* src = qkv + (size_t)n * 1536 + 1024 + h * 64 + cc;
  us8 v0 = *(const us8*)src;
  us8 v1 = *(const us8*)(src + 8);
  float se[16], ce[16];
#pragma unroll
  for (int q = 0; q < 4; q++) {
    *(f32x4*)(se + 4 * q) = *(const f32x4*)(sn + (size_t)n * 64 + cc + 4 * q);
    *(f32x4*)(ce + 4 * q) = *(const f32x4*)(cs + (size_t)n * 64 + cc + 4 * q);
  }
#pragma unroll
  for (int p = 0; p < 4; p++) {
    float a0 = b2f(v0[2 * p]), a1 = b2f(v0[2 * p + 1]);
    tile[i][cc + 2 * p]     = f2b(a0 * ce[2 * p] - a1 * se[2 * p]);
    tile[i][cc + 2 * p + 1] = f2b(a1 * ce[2 * p + 1] + a0 * se[2 * p + 1]);
    float b0 = b2f(v1[2 * p]), b1 = b2f(v1[2 * p + 1]);
    tile[i][cc + 8 + 2 * p]     = f2b(b0 * ce[8 + 2 * p] - b1 * se[8 + 2 * p]);
    tile[i][cc + 8 + 2 * p + 1] = f2b(b1 * ce[8 + 2 * p + 1] + b0 * se[8 + 2 * p + 1]);
  }
  __syncthreads();
  int dd = t >> 2;
  int nc = (t & 3) * 16;
  us8 r0, r1;
#pragma unroll
  for (int j = 0; j < 8; j++) { r0[j] = tile[nc + j][dd]; r1[j] = tile[nc + 8 + j][dd]; }
  unsigned short* dst = vt + ((size_t)h * 64 + dd) * NTOK + (size_t)nt * 64 + nc;
  *(us8*)dst = r0;
  *(us8*)(dst + 8) = r1;
}

// ---------------------------------------------------------------------------
// Windowed lookback attention, v3: 32x32 MFMA, swapped operands.
// block = (half, window, head), 4 waves x 32 q-rows. 8 chunks of 64 keys.
// ---------------------------------------------------------------------------
__global__ __launch_bounds__(256, 4) void attn_kernel(const unsigned short* __restrict__ qh,
                                                      const unsigned short* __restrict__ kh,
                                                      const unsigned short* __restrict__ vt,
                                                      unsigned short* __restrict__ ao) {
  __shared__ char kbuf[2][8192];   // 64 keys x 128B, unit-swizzled by (row&7)
  __shared__ char vbuf[8192];      // 64 d x 128B (64 keys), unit-swizzled by (d&7)
  int half = blockIdx.x, w = blockIdx.y, h = blockIdx.z;
  int t = threadIdx.x;
  int wave = t >> 6, l = t & 63;
  int l31 = l & 31, hi = l >> 5;
  const unsigned short* qb = qh + (size_t)h * NTOK * 64;
  const unsigned short* kb = kh + (size_t)h * NTOK * 64;
  const unsigned short* vb = vt + (size_t)h * 64 * NTOK;

  int qw = half * 128 + wave * 32 + l31;   // q within window
  int qn = w * 256 + qw;                   // global token
  s8 qf[4];
#pragma unroll
  for (int dht = 0; dht < 4; dht++)
    qf[dht] = *(const s8*)(qb + (size_t)qn * 64 + dht * 16 + hi * 8);

  f32x16 o0 = {}, o1 = {};
  float dsum = (w == 0) ? 128.f : 0.f;     // 256 zero-keys -> exp(0)=1, split across hi halves
  int n0 = w * 256 - 256;
  int c0 = (w == 0) ? 4 : 0;

  int srow = wave * 16 + (l >> 3);
  int sunit = l & 7;

  // prologue: stage K(c0)
  {
    const unsigned short* g = kb + (size_t)(n0 + c0 * 64 + srow) * 64 + ((sunit ^ (srow & 7)) * 8);
    gload_lds16(g, kbuf[c0 & 1] + wave * 2048);
    gload_lds16(g + 8 * 64, kbuf[c0 & 1] + wave * 2048 + 1024);
  }
  __syncthreads();

  for (int c = c0; c < 8; ++c) {
    int cb = n0 + c * 64;
    // stage V(c)
    {
      int d = srow;
      const unsigned short* g = vb + (size_t)d * NTOK + cb + ((sunit ^ (d & 7)) * 8);
      gload_lds16(g, vbuf + wave * 2048);
      gload_lds16(g + (size_t)8 * NTOK, vbuf + wave * 2048 + 1024);
    }
    // stage K(c+1)
    if (c < 7) {
      const unsigned short* g = kb + (size_t)(cb + 64 + srow) * 64 + ((sunit ^ (srow & 7)) * 8);
      gload_lds16(g, kbuf[(c + 1) & 1] + wave * 2048);
      gload_lds16(g + 8 * 64, kbuf[(c + 1) & 1] + wave * 2048 + 1024);
    }

    // QK^T (swapped): S^T tiles, 64 keys x 32 q
    f32x16 s[2] = {{}, {}};
    const char* kl = kbuf[c & 1];
#pragma unroll
    for (int kt = 0; kt < 2; kt++) {
#pragma unroll
      for (int dht = 0; dht < 4; dht++) {
        int row = kt * 32 + l31;
        int unit = (dht * 2 + hi) ^ (row & 7);
        s8 kf = *(const s8*)(kl + row * 128 + unit * 16);
        s[kt] = __builtin_amdgcn_mfma_f32_32x32x16_bf16(kf, qf[dht], s[kt], 0, 0, 0);
      }
    }

    // masked exp (no max-sub) + denominator + pack to bf16 pairs
    unsigned P0[2][4], P1[2][4];
#pragma unroll
    for (int kt = 0; kt < 2; kt++) {
#pragma unroll
      for (int r = 0; r < 16; r++) {
        int j = c * 64 + kt * 32 + (r & 3) + 8 * (r >> 2) + hi * 4;
        float e = (j <= qw + 256) ? __expf(s[kt][r] * 0.125f) : 0.f;
        s[kt][r] = e;
        dsum += e;
      }
#pragma unroll
      for (int j2 = 0; j2 < 4; j2++) {
        P0[kt][j2] = pk2(s[kt][j2 * 4 + 0], s[kt][j2 * 4 + 1]);
        P1[kt][j2] = pk2(s[kt][j2 * 4 + 2], s[kt][j2 * 4 + 3]);
      }
    }

    __syncthreads();   // V(c) staged (drains K(c+1) too)

    // PV (swapped): O^T += V^T(chunk) . P^T(chunk)
#pragma unroll
    for (int tt = 0; tt < 4; tt++) {
      int kt = tt >> 1, ss = tt & 1;
      unsigned a = P0[kt][2 * ss], b = P1[kt][2 * ss];
      unsigned cx = P0[kt][2 * ss + 1], dx = P1[kt][2 * ss + 1];
      asm volatile("v_permlane32_swap_b32 %0, %1" : "+v"(a), "+v"(cx));
      asm volatile("v_permlane32_swap_b32 %0, %1" : "+v"(b), "+v"(dx));
      s8 pf = mk_s8(a, b, cx, dx);
      {
        int row = l31;
        int unit = (tt * 2 + hi) ^ (row & 7);
        s8 vf = *(const s8*)(vbuf + row * 128 + unit * 16);
        o0 = __builtin_amdgcn_mfma_f32_32x32x16_bf16(vf, pf, o0, 0, 0, 0);
      }
      {
        int row = 32 + l31;
        int unit = (tt * 2 + hi) ^ (row & 7);
        s8 vf = *(const s8*)(vbuf + row * 128 + unit * 16);
        o1 = __builtin_amdgcn_mfma_f32_32x32x16_bf16(vf, pf, o1, 0, 0, 0);
      }
    }
    __syncthreads();   // LDS consumed; next iter may overwrite
  }

  dsum += __shfl_xor(dsum, 32);
  float inv = 1.f / dsum;

  unsigned short* orow = ao + (size_t)qn * INNER_ + h * 64;
#pragma unroll
  for (int g = 0; g < 4; g++) {
    us4 st0, st1;
#pragma unroll
    for (int rr = 0; rr < 4; rr++) {
      st0[rr] = f2b(o0[g * 4 + rr] * inv);
      st1[rr] = f2b(o1[g * 4 + rr] * inv);
    }
    *(us4*)(orow + g * 8 + hi * 4) = st0;
    *(us4*)(orow + 32 + g * 8 + hi * 4) = st1;
  }
}

// ---------------------------------------------------------------------------
extern "C" void kernel_launch(void* const* d_in, const int* in_sizes, int n_in,
                              void* d_out, int out_size, void* d_ws, size_t ws_size,
                              hipStream_t stream) {
  const float* x     = (const float*)d_in[0];
  const float* sin_  = (const float*)d_in[1];
  const float* cos_  = (const float*)d_in[2];
  const float* gamma = (const float*)d_in[3];
  const float* beta  = (const float*)d_in[4];
  const float* w_qkv = (const float*)d_in[5];
  const float* w_out = (const float*)d_in[6];
  const float* b_out = (const float*)d_in[7];

  // ws layout (bytes). total needed = 205,520,896 (~196 MiB)
  char* ws = (char*)d_ws;
  const size_t OFF_WQT = 0;                    // 1536*1024*2 = 3,145,728
  const size_t OFF_WOT = 3145728;              // 1024*512*2  = 1,048,576
  const size_t OFF_XS  = 4194304;              // 32768*1024*2 = 67,108,864
  const size_t OFF_QKV = 71303168;             // 32768*1536*2 = 100,663,296
  const size_t OFF_VT  = 171966464;            // 8*64*32768*2 = 33,554,432
  const size_t NEEDED  = 205520896;
  if (ws_size < NEEDED) return;  // fail loudly (output stays poisoned)

  unsigned short* wqT = (unsigned short*)(ws + OFF_WQT);
  unsigned short* woT = (unsigned short*)(ws + OFF_WOT);
  unsigned short* xs  = (unsigned short*)(ws + OFF_XS);
  unsigned short* qkv = (unsigned short*)(ws + OFF_QKV);
  unsigned short* vt  = (unsigned short*)(ws + OFF_VT);
  unsigned short* qh  = xs;                                   // reuse xs after gemm1
  unsigned short* kh  = (unsigned short*)(ws + OFF_XS + 33554432);
  unsigned short* ao  = qkv;                                  // reuse qkv after rotary

  transpose_f32_bf16<<<dim3(1536 / 32, 1024 / 32), dim3(32, 8), 0, stream>>>(w_qkv, wqT, 1024, 1536);
  transpose_f32_bf16<<<dim3(1024 / 32, 512 / 32), dim3(32, 8), 0, stream>>>(w_out, woT, 512, 1024);
  ln_shift<<<NTOK, 256, 0, stream>>>(x, gamma, beta, xs);
  gemm_nt_p8<false><<<dim3(1536 / 256, NTOK / 256), 512, 0, stream>>>(xs, wqT, qkv, nullptr, NTOK, 1536, 1024);
  rotary_qk<<<(NTOK * 128) / 256, 256, 0, stream>>>(qkv, sin_, cos_, qh, kh);
  rotary_vT<<<dim3(NTOK / 64, HEADS_), 256, 0, stream>>>(qkv, sin_, cos_, vt);
  attn_kernel<<<dim3(2, NWIN_, HEADS_), 256, 0, stream>>>(qh, kh, vt, ao);
  gemm_nt_p8<true><<<dim3(1024 / 256, NTOK / 256), 512, 0, stream>>>(ao, woT, (void*)d_out, b_out, NTOK, 1024, 512);
}